// Round 13
// baseline (190.742 us; speedup 1.0000x reference)
//
#include <hip/hip_runtime.h>

// GAT 2-layer: N=100000, IN=256, L1: heads=8 x 8, L2: heads=1 x 40.
// R13 = R12 fusion, fixed: (1) scatter/gemm1 roles INTERLEAVED by blockIdx
// (bid%4==0 -> scatter while slots last) so scatter stalls hide under gemm1
// MFMA on the same CU instead of forming a serial low-occupancy phase;
// (2) gemm1's hs tile aliases xs (dead after MFMA loop) -> LDS 44->34.8KB
// -> 4 blocks/CU for both paths. Everything else identical to R12.

#define L_IN   256
#define L_C1   64
#define L_H1   8
#define L_OUT  40
#define BCAP   5120     // bucket capacity (mean 4092, sigma ~64)

typedef __attribute__((ext_vector_type(8))) short short8;
typedef __attribute__((ext_vector_type(4))) float f32x4;

__device__ __forceinline__ float leaky(float x){ return fmaxf(x, 0.2f*x); }
__device__ __forceinline__ unsigned f2bf(float f){
  unsigned u = __float_as_uint(f);
  return (u + 0x7fffu + ((u >> 16) & 1u)) >> 16;     // RNE
}
__device__ __forceinline__ float bflo(unsigned u){ return __uint_as_float(u << 16); }
__device__ __forceinline__ float bfhi(unsigned u){ return __uint_as_float(u & 0xffff0000u); }

// ---------------- prep: W1 -> wt (bf16 transposed); block 4 zeros gcur ----------------
__global__ __launch_bounds__(256) void prep_w1(const float* __restrict__ W1,
                                               ushort* __restrict__ wt,
                                               int* __restrict__ gcur, int NB){
  const int t = threadIdx.x;
  if (blockIdx.x == 4){
    for (int i = t; i < NB; i += 256) gcur[i] = 0;
    return;
  }
  __shared__ float ws[64][65];
  const int kb = blockIdx.x;            // 4 blocks, one K-chunk each
  #pragma unroll
  for (int i = 0; i < 16; ++i){
    int idx = t + i*256;
    ws[idx >> 6][idx & 63] = W1[(size_t)(kb*64 + (idx >> 6))*64 + (idx & 63)];
  }
  __syncthreads();
  int c  = t >> 2;
  int j0 = (t & 3) * 16;
  ushort tmp[16];
  #pragma unroll
  for (int j = 0; j < 16; ++j) tmp[j] = (ushort)f2bf(ws[j0 + j][c]);
  uint4* dst = (uint4*)(wt + (size_t)c*256 + kb*64 + j0);
  dst[0] = *(uint4*)&tmp[0];
  dst[1] = *(uint4*)&tmp[8];
}

// ---------------- FUSED: bin_scatter (every R-th block) || gemm1 ----------------
// Entry = src | (local_dst << 17)  [N < 131072].
__global__ __launch_bounds__(256) void scatter_gemm1(
    const int* __restrict__ esrc, const int* __restrict__ edst,
    int* __restrict__ gcur, unsigned* __restrict__ binned, int E, int NB, int NSC, int R,
    const float* __restrict__ x, const ushort* __restrict__ wt,
    const float* __restrict__ atts, const float* __restrict__ attd,
    ushort* __restrict__ h1b, float* __restrict__ as1, float* __restrict__ ad1, int n)
{
  __shared__ __align__(16) char smem[34816];
  const int t   = threadIdx.x;
  const int bid = blockIdx.x;
  const bool is_scatter = ((bid % R) == 0) && ((bid / R) < NSC);

  if (is_scatter){
    // ---- bin_scatter path (LDS: 3 x 512 ints = 6KB of the union) ----
    int* hist  = (int*)smem;
    int* rbase = hist + 512;
    int* cur   = rbase + 512;
    const int e0 = (bid / R) * 4096;
    hist[t] = 0; hist[t+256] = 0; cur[t] = 0; cur[t+256] = 0;
    __syncthreads();
    int sv[16], dv[16];
    const bool full = (e0 + 4096 <= E);
    if (full){
      #pragma unroll
      for (int j = 0; j < 4; ++j){
        int p4 = (e0 >> 2) + j*256 + t;
        int4 s4 = ((const int4*)esrc)[p4];
        int4 d4 = ((const int4*)edst)[p4];
        sv[4*j+0]=s4.x; sv[4*j+1]=s4.y; sv[4*j+2]=s4.z; sv[4*j+3]=s4.w;
        dv[4*j+0]=d4.x; dv[4*j+1]=d4.y; dv[4*j+2]=d4.z; dv[4*j+3]=d4.w;
        atomicAdd(&hist[d4.x >> 8], 1); atomicAdd(&hist[d4.y >> 8], 1);
        atomicAdd(&hist[d4.z >> 8], 1); atomicAdd(&hist[d4.w >> 8], 1);
      }
    } else {
      #pragma unroll
      for (int j = 0; j < 16; ++j){
        int idx = e0 + j*256 + t;
        if (idx < E){
          sv[j] = esrc[idx]; dv[j] = edst[idx];
          atomicAdd(&hist[dv[j] >> 8], 1);
        } else dv[j] = -1;
      }
    }
    __syncthreads();
    if (hist[t])                   rbase[t]     = atomicAdd(&gcur[t],     hist[t]);
    if (t+256 < NB && hist[t+256]) rbase[t+256] = atomicAdd(&gcur[t+256], hist[t+256]);
    __syncthreads();
    #pragma unroll
    for (int j = 0; j < 16; ++j){
      if (dv[j] >= 0){
        int b = dv[j] >> 8;
        int off = rbase[b] + atomicAdd(&cur[b], 1);
        if (off < BCAP)
          binned[(size_t)b*BCAP + off] =
            (unsigned)sv[j] | ((unsigned)(dv[j] & 255) << 17);
      }
    }
    return;
  }

  // ---- gemm1 path (LDS: xs 17408 + ws 17408; hs ALIASES xs after MFMA) ----
  ushort (*xs)[136] = (ushort(*)[136])(smem);
  ushort (*ws)[136] = (ushort(*)[136])(smem + 17408);
  ushort (*hs)[72]  = (ushort(*)[72]) (smem);          // aliases xs (dead)
  const int gid = bid - min(bid/R + ((bid % R) ? 1 : 0), NSC);
  const int rb = gid * 64;
  const int wv = t >> 6;
  const int ln = t & 63;
  const int fr = ln & 15;
  const int fq = ln >> 4;

  f32x4 acc[4];
  #pragma unroll
  for (int cb = 0; cb < 4; ++cb) acc[cb] = (f32x4){0.f,0.f,0.f,0.f};

  for (int kb = 0; kb < 2; ++kb){
    if (kb) __syncthreads();
    #pragma unroll
    for (int i = 0; i < 8; ++i){
      int idx = t + i*256;
      int row = idx >> 5, c4 = idx & 31;
      float4 v = make_float4(0.f,0.f,0.f,0.f);
      if (rb + row < n) v = *(const float4*)(x + (size_t)(rb+row)*L_IN + kb*128 + c4*4);
      uint2 p;
      p.x = f2bf(v.x) | (f2bf(v.y) << 16);
      p.y = f2bf(v.z) | (f2bf(v.w) << 16);
      *(uint2*)&xs[row][c4*4] = p;
    }
    #pragma unroll
    for (int i = 0; i < 4; ++i){
      int idx = t + i*256;
      int row = idx >> 4, c8 = idx & 15;
      *(uint4*)&ws[row][c8*8] = *(const uint4*)(wt + (size_t)row*256 + kb*128 + c8*8);
    }
    __syncthreads();
    #pragma unroll
    for (int ks = 0; ks < 4; ++ks){
      short8 a = *(const short8*)&xs[wv*16 + fr][ks*32 + fq*8];
      #pragma unroll
      for (int cb = 0; cb < 4; ++cb){
        short8 b = *(const short8*)&ws[cb*16 + fr][ks*32 + fq*8];
        acc[cb] = __builtin_amdgcn_mfma_f32_16x16x32_bf16(a, b, acc[cb], 0, 0, 0);
      }
    }
  }
  __syncthreads();                       // xs dead from here; hs takes over
  #pragma unroll
  for (int cb = 0; cb < 4; ++cb)
    #pragma unroll
    for (int r = 0; r < 4; ++r)
      hs[wv*16 + fq*4 + r][cb*16 + fr] = (ushort)f2bf(acc[cb][r]);
  __syncthreads();
  #pragma unroll
  for (int p = 0; p < 2; ++p){
    int pid = t + p*256;
    int row = pid >> 3, hd = pid & 7;
    if (rb + row < n){
      uint4 u = *(const uint4*)&hs[row][hd*8];
      float v0=bflo(u.x), v1=bfhi(u.x), v2=bflo(u.y), v3=bfhi(u.y);
      float v4=bflo(u.z), v5=bfhi(u.z), v6=bflo(u.w), v7=bfhi(u.w);
      const float* sa = atts + hd*8;
      const float* da = attd + hd*8;
      float ds = v0*sa[0]+v1*sa[1]+v2*sa[2]+v3*sa[3]+v4*sa[4]+v5*sa[5]+v6*sa[6]+v7*sa[7];
      float dd = v0*da[0]+v1*da[1]+v2*da[2]+v3*da[3]+v4*da[4]+v5*da[5]+v6*da[6]+v7*da[7];
      as1[(size_t)(rb+row)*L_H1 + hd] = ds;
      ad1[(size_t)(rb+row)*L_H1 + hd] = dd;
    }
  }
  #pragma unroll
  for (int i = 0; i < 2; ++i){
    int idx = t + i*256;
    int row = idx >> 3, c8 = idx & 7;
    if (rb + row < n)
      *(uint4*)(h1b + (size_t)(rb+row)*L_C1 + c8*8) = *(const uint4*)&hs[row][c8*8];
  }
}

// ---------------- bucket_csr: LDS-staged per-bucket CSR ----------------
__global__ __launch_bounds__(256) void bucket_csr(const unsigned* __restrict__ binned,
    const int* __restrict__ gcur, int2* __restrict__ nodeptr, int* __restrict__ csr,
    int N){
  __shared__ unsigned ebuf[BCAP];
  __shared__ int cnt[256], pref[256], cur[256];
  const int t = threadIdx.x;
  const int b = blockIdx.x;
  int ne = gcur[b]; if (ne > BCAP) ne = BCAP;
  const int base = b * BCAP;
  cnt[t] = 0; cur[t] = 0;
  __syncthreads();
  for (int i = t; i < ne; i += 256){
    unsigned e = binned[base + i];
    ebuf[i] = e;
    atomicAdd(&cnt[(e >> 17) & 255u], 1);
  }
  __syncthreads();
  pref[t] = cnt[t];
  __syncthreads();
  for (int off = 1; off < 256; off <<= 1){
    int a = (t >= off) ? pref[t-off] : 0;
    __syncthreads();
    pref[t] += a;
    __syncthreads();
  }
  int excl = pref[t] - cnt[t];
  __syncthreads();
  pref[t] = excl;
  int d = (b << 8) + t;
  if (d < N) nodeptr[d] = make_int2(base + excl, cnt[t]);
  __syncthreads();
  for (int i = t; i < ne; i += 256){
    unsigned e = ebuf[i];
    int ln = (int)((e >> 17) & 255u);
    int pos = base + pref[ln] + atomicAdd(&cur[ln], 1);
    csr[pos] = (int)(e & 0x1FFFFu);
  }
}

// ---------------- AGG1: single-pass softmax-aggregate + bias + relu (bf16 out) ----------------
__global__ __launch_bounds__(256) void agg1_kernel(
    const int2* __restrict__ nodeptr, const int* __restrict__ csr,
    const ushort* __restrict__ h1b, const float* __restrict__ as1,
    const float* __restrict__ ad1, const float* __restrict__ b1,
    ushort* __restrict__ hrb, int n)
{
  int wid  = (blockIdx.x*blockDim.x + threadIdx.x) >> 6;
  int lane = threadIdx.x & 63;
  if (wid >= n) return;
  int2 np  = nodeptr[wid];
  int beg  = np.x;
  int degt = np.y + 1;                    // + virtual self-loop

  const int h  = lane & 7;    // head (weight layout)
  const int eg = lane >> 3;   // edge-in-group (weight layout)
  const int cp = lane & 31;   // channel pair (acc layout)
  const int ep = lane >> 5;   // edge parity (acc layout)
  const int hc = cp >> 2;     // this lane's head in acc layout

  float adn = ad1[(size_t)wid*L_H1 + h];
  float ax = 0.f, ay = 0.f, sp = 0.f;

  #define A1_GRP_W(g, SRCV, WV)                                            \
    { int i_ = (g)*8 + eg;                                                 \
      SRCV = (i_ < degt-1) ? csr[beg + i_] : wid;                          \
      float l_ = (i_ < degt) ? leaky(as1[(size_t)SRCV*L_H1 + h] + adn)     \
                             : -1e30f;                                     \
      WV = __expf(l_); sp += WV; }
  #define A1_GRP_G(SRCV, WV)                                               \
    _Pragma("unroll")                                                      \
    for (int e0 = 0; e0 < 8; e0 += 2){                                     \
      int e_  = e0 + ep;                                                   \
      float we_ = __shfl(WV,   e_*8 + hc);                                 \
      int   se_ = __shfl(SRCV, e_*8);                                      \
      unsigned u_ = *(const unsigned*)(h1b + (size_t)se_*L_C1 + cp*2);     \
      ax += we_ * bflo(u_);                                                \
      ay += we_ * bfhi(u_);                                                \
    }

  if (degt <= 16){
    int s0, s1; float w0, w1;
    A1_GRP_W(0, s0, w0) A1_GRP_W(1, s1, w1)
    A1_GRP_G(s0, w0) A1_GRP_G(s1, w1)
  } else if (degt <= 24){
    int s0, s1, s2; float w0, w1, w2;
    A1_GRP_W(0, s0, w0) A1_GRP_W(1, s1, w1) A1_GRP_W(2, s2, w2)
    A1_GRP_G(s0, w0) A1_GRP_G(s1, w1) A1_GRP_G(s2, w2)
  } else {
    const int ngrp = (degt + 7) >> 3;
    for (int g = 0; g < ngrp; ++g){
      int sg; float wg;
      A1_GRP_W(g, sg, wg)
      A1_GRP_G(sg, wg)
    }
  }
  #undef A1_GRP_W
  #undef A1_GRP_G

  #pragma unroll
  for (int off = 8; off < 64; off <<= 1) sp += __shfl_xor(sp, off);
  float rinv = 1.0f / __shfl(sp, hc);
  ax += __shfl_xor(ax, 32);
  ay += __shfl_xor(ay, 32);
  if (lane < 32){
    float2 bv = *(const float2*)&b1[cp*2];
    float r0 = fmaxf(ax*rinv + bv.x, 0.f);
    float r1 = fmaxf(ay*rinv + bv.y, 0.f);
    *(unsigned*)(hrb + (size_t)wid*L_C1 + cp*2) = f2bf(r0) | (f2bf(r1) << 16);
  }
}

// ---------------- GEMM2: h2 = hrelu @ W2 (+att dots), reg-resident rows ----------------
__global__ __launch_bounds__(256) void gemm2_kernel(
    const ushort* __restrict__ hrb, const float* __restrict__ W2,
    const float* __restrict__ atts2, const float* __restrict__ attd2,
    ushort* __restrict__ h2b, float* __restrict__ as2, float* __restrict__ ad2, int n)
{
  __shared__ float w2s[64*40];
  const int t = threadIdx.x;
  for (int i = t; i < 64*40; i += 256) w2s[i] = W2[i];
  __syncthreads();
  int row = blockIdx.x*256 + t;
  if (row >= n) return;

  uint4 rv[8];
  #pragma unroll
  for (int q = 0; q < 8; ++q)
    rv[q] = *(const uint4*)(hrb + (size_t)row*L_C1 + q*8);

  f32x4 acc4[10];
  #pragma unroll
  for (int j = 0; j < 10; ++j) acc4[j] = (f32x4){0.f,0.f,0.f,0.f};

  #pragma unroll
  for (int q = 0; q < 8; ++q){
    unsigned uu[4] = {rv[q].x, rv[q].y, rv[q].z, rv[q].w};
    #pragma unroll
    for (int d = 0; d < 4; ++d){
      int k = q*8 + d*2;
      float v0 = bflo(uu[d]), v1 = bfhi(uu[d]);
      const f32x4* w0 = (const f32x4*)&w2s[k*40];
      const f32x4* w1 = (const f32x4*)&w2s[(k+1)*40];
      #pragma unroll
      for (int j = 0; j < 10; ++j) acc4[j] += v0*w0[j] + v1*w1[j];
    }
  }

  float acc[40];
  #pragma unroll
  for (int j = 0; j < 10; ++j){
    acc[4*j+0]=acc4[j][0]; acc[4*j+1]=acc4[j][1];
    acc[4*j+2]=acc4[j][2]; acc[4*j+3]=acc4[j][3];
  }
  float ps = 0.f, pd = 0.f;
  #pragma unroll
  for (int j = 0; j < 40; ++j){ ps += acc[j]*atts2[j]; pd += acc[j]*attd2[j]; }
  unsigned pk[20];
  #pragma unroll
  for (int q = 0; q < 20; ++q) pk[q] = f2bf(acc[2*q]) | (f2bf(acc[2*q+1]) << 16);
  uint4* dst = (uint4*)(h2b + (size_t)row*L_OUT);
  #pragma unroll
  for (int q = 0; q < 5; ++q) dst[q] = make_uint4(pk[4*q],pk[4*q+1],pk[4*q+2],pk[4*q+3]);
  as2[row] = ps;
  ad2[row] = pd;
}

// ---------------- AGG2 + bias + log_softmax: 3-edge x 20-chpair, tiered ----------------
__global__ __launch_bounds__(256) void agg2_kernel(
    const int2* __restrict__ nodeptr, const int* __restrict__ csr,
    const ushort* __restrict__ h2b, const float* __restrict__ as2,
    const float* __restrict__ ad2, const float* __restrict__ b2,
    float* __restrict__ out, int n)
{
  int wid  = (blockIdx.x*blockDim.x + threadIdx.x) >> 6;
  int lane = threadIdx.x & 63;
  if (wid >= n) return;
  int2 np  = nodeptr[wid];
  int beg  = np.x;
  int degt = np.y + 1;

  const int eidx = (lane < 60) ? (lane / 20) : 0;   // edge-in-step (0..2)
  const int cq   = (lane < 60) ? (lane % 20) : 0;   // channel pair (0..19)

  float adn = ad2[wid];
  float ax = 0.f, ay = 0.f, sp = 0.f;

  #define A2_STEP(e_, SRCV, WV, CNT)                                       \
    { int ee_ = (e_);                                                      \
      int es_ = (ee_ < 64) ? ee_ : 63;                                     \
      float we_ = __shfl(WV,   es_);                                       \
      int   se_ = __shfl(SRCV, es_);                                       \
      we_ = (ee_ < (CNT)) ? we_ : 0.f;                                     \
      unsigned u_ = *(const unsigned*)(h2b + (size_t)se_*L_OUT + cq*2);    \
      ax += we_ * bflo(u_);                                                \
      ay += we_ * bfhi(u_); }

  if (degt <= 64){
    int i = lane;
    int src = (i < degt-1) ? csr[beg + i] : wid;
    float l = (i < degt) ? leaky(as2[src] + adn) : -1e30f;
    float w = __expf(l);
    sp = w;
    if (degt <= 18){
      #pragma unroll
      for (int j = 0; j < 2; ++j){
        A2_STEP(j*9 + 0*3 + eidx, src, w, degt)
        A2_STEP(j*9 + 1*3 + eidx, src, w, degt)
        A2_STEP(j*9 + 2*3 + eidx, src, w, degt)
      }
    } else if (degt <= 27){
      #pragma unroll
      for (int j = 0; j < 3; ++j){
        A2_STEP(j*9 + 0*3 + eidx, src, w, degt)
        A2_STEP(j*9 + 1*3 + eidx, src, w, degt)
        A2_STEP(j*9 + 2*3 + eidx, src, w, degt)
      }
    } else if (degt <= 36){
      #pragma unroll
      for (int j = 0; j < 4; ++j){
        A2_STEP(j*9 + 0*3 + eidx, src, w, degt)
        A2_STEP(j*9 + 1*3 + eidx, src, w, degt)
        A2_STEP(j*9 + 2*3 + eidx, src, w, degt)
      }
    } else {
      for (int e0 = 0; e0 < degt; e0 += 9){
        A2_STEP(e0 + 0*3 + eidx, src, w, degt)
        A2_STEP(e0 + 1*3 + eidx, src, w, degt)
        A2_STEP(e0 + 2*3 + eidx, src, w, degt)
      }
    }
  } else {
    const int ngrp = (degt + 63) >> 6;
    for (int g = 0; g < ngrp; ++g){
      int i = g*64 + lane;
      int src = (i < degt-1) ? csr[beg + i] : wid;
      float l = (i < degt) ? leaky(as2[src] + adn) : -1e30f;
      float w = __expf(l);
      sp += w;
      int cnt = degt - g*64; if (cnt > 64) cnt = 64;
      for (int e0 = 0; e0 < cnt; e0 += 9){
        A2_STEP(e0 + 0*3 + eidx, src, w, cnt)
        A2_STEP(e0 + 1*3 + eidx, src, w, cnt)
        A2_STEP(e0 + 2*3 + eidx, src, w, cnt)
      }
    }
  }
  #undef A2_STEP

  #pragma unroll
  for (int off = 1; off < 64; off <<= 1) sp += __shfl_xor(sp, off);
  float rinv = 1.0f / sp;

  // cross-eidx reduction: channel cq lives in lanes {cq, cq+20, cq+40}
  float ax0 = __shfl(ax, cq), ax1 = __shfl(ax, cq+20), ax2 = __shfl(ax, cq+40);
  float ay0 = __shfl(ay, cq), ay1 = __shfl(ay, cq+20), ay2 = __shfl(ay, cq+40);
  float axs = (ax0 + ax1) + ax2;
  float ays = (ay0 + ay1) + ay2;

  bool act = (lane < 20);
  float o0 = axs*rinv + b2[cq*2];
  float o1 = ays*rinv + b2[cq*2+1];
  float mx = act ? fmaxf(o0, o1) : -1e30f;
  #pragma unroll
  for (int off = 1; off < 32; off <<= 1) mx = fmaxf(mx, __shfl_xor(mx, off));
  float ex = act ? (__expf(o0 - mx) + __expf(o1 - mx)) : 0.f;
  #pragma unroll
  for (int off = 1; off < 32; off <<= 1) ex += __shfl_xor(ex, off);
  float lse = mx + __logf(ex);
  if (act){
    float2 r = make_float2(o0 - lse, o1 - lse);
    *(float2*)(out + (size_t)wid*L_OUT + cq*2) = r;
  }
}

// ---------------- launch ----------------
extern "C" void kernel_launch(void* const* d_in, const int* in_sizes, int n_in,
                              void* d_out, int out_size, void* d_ws, size_t ws_size,
                              hipStream_t stream)
{
  const float* x    = (const float*)d_in[0];
  const int*   ei   = (const int*)  d_in[1];
  const float* W1   = (const float*)d_in[2];
  const float* as1w = (const float*)d_in[3];
  const float* ad1w = (const float*)d_in[4];
  const float* b1   = (const float*)d_in[5];
  const float* W2   = (const float*)d_in[6];
  const float* as2w = (const float*)d_in[7];
  const float* ad2w = (const float*)d_in[8];
  const float* b2   = (const float*)d_in[9];

  const int N = in_sizes[0] / L_IN;
  const int E = in_sizes[1] / 2;
  const int NB = (N + 255) >> 8;          // buckets of 256 nodes (<=512)
  const int NSC = (E + 4095) / 4096;      // scatter blocks
  const int NG1 = (N + 63) / 64;          // gemm1 blocks
  int R = (NSC + NG1) / NSC; if (R < 2) R = 2;   // interleave stride
  const int* esrc = ei;
  const int* edst = ei + E;
  float* out = (float*)d_out;

  char* w = (char*)d_ws;
  auto alloc = [&](size_t bytes)->char*{
    char* p = w; w += (bytes + 255) & ~size_t(255); return p;
  };
  ushort* h1b  = (ushort*)alloc((size_t)N*L_C1*2);
  float*  as1  = (float*) alloc((size_t)N*L_H1*4);
  float*  ad1  = (float*) alloc((size_t)N*L_H1*4);
  // union: binned (NB*BCAP*4, dead after bucket_csr) aliases hrb+h2b
  size_t union_sz = (size_t)N*L_C1*2 + (size_t)N*L_OUT*2;
  if (union_sz < (size_t)NB*BCAP*4) union_sz = (size_t)NB*BCAP*4;
  char*  ub    = alloc(union_sz);
  ushort* hrb  = (ushort*)ub;
  ushort* h2b  = (ushort*)(ub + (size_t)N*L_C1*2);
  unsigned* binned = (unsigned*)ub;
  float*  as2  = (float*) alloc((size_t)N*4);
  float*  ad2  = (float*) alloc((size_t)N*4);
  ushort* wt   = (ushort*)alloc((size_t)64*256*2);
  int2*  nodeptr=(int2*)  alloc((size_t)N*8);
  int*   csr   = (int*)   alloc((size_t)NB*BCAP*4);
  int*   gcur  = (int*)   alloc((size_t)NB*4);

  prep_w1     <<<5,          256, 0, stream>>>(W1, wt, gcur, NB);
  scatter_gemm1<<<NSC + NG1, 256, 0, stream>>>(esrc, edst, gcur, binned, E, NB, NSC, R,
                                               x, wt, as1w, ad1w, h1b, as1, ad1, N);
  bucket_csr  <<<NB,         256, 0, stream>>>(binned, gcur, nodeptr, csr, N);
  agg1_kernel <<<(N+3)/4,    256, 0, stream>>>(nodeptr, csr, h1b, as1, ad1, b1, hrb, N);
  gemm2_kernel<<<(N+255)/256,256, 0, stream>>>(hrb, W2, as2w, ad2w, h2b, as2, ad2, N);
  agg2_kernel <<<(N+3)/4,    256, 0, stream>>>(nodeptr, csr, h2b, as2, ad2, b2, out, N);
}

// Round 14
// 185.509 us; speedup vs baseline: 1.0282x; 1.0282x over previous
//
#include <hip/hip_runtime.h>

// GAT 2-layer: N=100000, IN=256, L1: heads=8 x 8, L2: heads=1 x 40.
// R14: DE-FUSE scatter/gemm1 (R12/R13 fusion was 68us with 1.7% MfmaUtil in
// both variants -- opaque; standalone counters restore attribution).
// gemm1: chunk-2 register prefetch (T14 async-stage) hides the 2nd HBM
// latency exposure; hs aliases xs -> 34.8KB LDS, 4 blocks/CU.
// bucket_csr: 512 threads (stage/scatter on 8 waves; scan on first 256).

#define L_IN   256
#define L_C1   64
#define L_H1   8
#define L_OUT  40
#define BCAP   5120     // bucket capacity (mean 4092, sigma ~64)

typedef __attribute__((ext_vector_type(8))) short short8;
typedef __attribute__((ext_vector_type(4))) float f32x4;

__device__ __forceinline__ float leaky(float x){ return fmaxf(x, 0.2f*x); }
__device__ __forceinline__ unsigned f2bf(float f){
  unsigned u = __float_as_uint(f);
  return (u + 0x7fffu + ((u >> 16) & 1u)) >> 16;     // RNE
}
__device__ __forceinline__ float bflo(unsigned u){ return __uint_as_float(u << 16); }
__device__ __forceinline__ float bfhi(unsigned u){ return __uint_as_float(u & 0xffff0000u); }

// ---------------- prep: W1 -> wt (bf16 transposed); block 4 zeros gcur ----------------
__global__ __launch_bounds__(256) void prep_w1(const float* __restrict__ W1,
                                               ushort* __restrict__ wt,
                                               int* __restrict__ gcur, int NB){
  const int t = threadIdx.x;
  if (blockIdx.x == 4){
    for (int i = t; i < NB; i += 256) gcur[i] = 0;
    return;
  }
  __shared__ float ws[64][65];
  const int kb = blockIdx.x;            // 4 blocks, one K-chunk each
  #pragma unroll
  for (int i = 0; i < 16; ++i){
    int idx = t + i*256;
    ws[idx >> 6][idx & 63] = W1[(size_t)(kb*64 + (idx >> 6))*64 + (idx & 63)];
  }
  __syncthreads();
  int c  = t >> 2;
  int j0 = (t & 3) * 16;
  ushort tmp[16];
  #pragma unroll
  for (int j = 0; j < 16; ++j) tmp[j] = (ushort)f2bf(ws[j0 + j][c]);
  uint4* dst = (uint4*)(wt + (size_t)c*256 + kb*64 + j0);
  dst[0] = *(uint4*)&tmp[0];
  dst[1] = *(uint4*)&tmp[8];
}

// ---------------- bin_scatter: standalone (6KB LDS -> 8 blocks/CU) ----------------
// Entry = src | (local_dst << 17)  [N < 131072].
__global__ __launch_bounds__(256) void bin_scatter(const int* __restrict__ esrc,
    const int* __restrict__ edst, int* __restrict__ gcur,
    unsigned* __restrict__ binned, int E, int NB){
  __shared__ int hist[512], rbase[512], cur[512];
  const int t  = threadIdx.x;
  const int e0 = blockIdx.x * 4096;
  hist[t] = 0; hist[t+256] = 0; cur[t] = 0; cur[t+256] = 0;
  __syncthreads();
  int sv[16], dv[16];
  const bool full = (e0 + 4096 <= E);
  if (full){
    #pragma unroll
    for (int j = 0; j < 4; ++j){
      int p4 = (e0 >> 2) + j*256 + t;
      int4 s4 = ((const int4*)esrc)[p4];
      int4 d4 = ((const int4*)edst)[p4];
      sv[4*j+0]=s4.x; sv[4*j+1]=s4.y; sv[4*j+2]=s4.z; sv[4*j+3]=s4.w;
      dv[4*j+0]=d4.x; dv[4*j+1]=d4.y; dv[4*j+2]=d4.z; dv[4*j+3]=d4.w;
      atomicAdd(&hist[d4.x >> 8], 1); atomicAdd(&hist[d4.y >> 8], 1);
      atomicAdd(&hist[d4.z >> 8], 1); atomicAdd(&hist[d4.w >> 8], 1);
    }
  } else {
    #pragma unroll
    for (int j = 0; j < 16; ++j){
      int idx = e0 + j*256 + t;
      if (idx < E){
        sv[j] = esrc[idx]; dv[j] = edst[idx];
        atomicAdd(&hist[dv[j] >> 8], 1);
      } else dv[j] = -1;
    }
  }
  __syncthreads();
  if (hist[t])                   rbase[t]     = atomicAdd(&gcur[t],     hist[t]);
  if (t+256 < NB && hist[t+256]) rbase[t+256] = atomicAdd(&gcur[t+256], hist[t+256]);
  __syncthreads();
  #pragma unroll
  for (int j = 0; j < 16; ++j){
    if (dv[j] >= 0){
      int b = dv[j] >> 8;
      int off = rbase[b] + atomicAdd(&cur[b], 1);
      if (off < BCAP)
        binned[(size_t)b*BCAP + off] =
          (unsigned)sv[j] | ((unsigned)(dv[j] & 255) << 17);
    }
  }
}

// ---------------- GEMM1: chunk-2 register prefetch, hs aliases xs ----------------
__global__ __launch_bounds__(256) void gemm1_kernel(
    const float* __restrict__ x, const ushort* __restrict__ wt,
    const float* __restrict__ atts, const float* __restrict__ attd,
    ushort* __restrict__ h1b, float* __restrict__ as1, float* __restrict__ ad1, int n)
{
  __shared__ __align__(16) char smem[34816];
  ushort (*xs)[136] = (ushort(*)[136])(smem);
  ushort (*ws)[136] = (ushort(*)[136])(smem + 17408);
  ushort (*hs)[72]  = (ushort(*)[72]) (smem);          // aliases xs (dead after MFMA)
  const int t  = threadIdx.x;
  const int rb = blockIdx.x * 64;
  const int wv = t >> 6;
  const int ln = t & 63;
  const int fr = ln & 15;
  const int fq = ln >> 4;

  // ---- stage chunk 0 into LDS ----
  #pragma unroll
  for (int i = 0; i < 8; ++i){
    int idx = t + i*256;
    int row = idx >> 5, c4 = idx & 31;
    float4 v = make_float4(0.f,0.f,0.f,0.f);
    if (rb + row < n) v = *(const float4*)(x + (size_t)(rb+row)*L_IN + c4*4);
    uint2 p;
    p.x = f2bf(v.x) | (f2bf(v.y) << 16);
    p.y = f2bf(v.z) | (f2bf(v.w) << 16);
    *(uint2*)&xs[row][c4*4] = p;
  }
  #pragma unroll
  for (int i = 0; i < 4; ++i){
    int idx = t + i*256;
    int row = idx >> 4, c8 = idx & 15;
    *(uint4*)&ws[row][c8*8] = *(const uint4*)(wt + (size_t)row*256 + c8*8);
  }
  __syncthreads();

  // ---- prefetch chunk 1 into registers (hides under chunk-0 MFMA) ----
  float4 px[8]; uint4 pw[4];
  #pragma unroll
  for (int i = 0; i < 8; ++i){
    int idx = t + i*256;
    int row = idx >> 5, c4 = idx & 31;
    px[i] = make_float4(0.f,0.f,0.f,0.f);
    if (rb + row < n) px[i] = *(const float4*)(x + (size_t)(rb+row)*L_IN + 128 + c4*4);
  }
  #pragma unroll
  for (int i = 0; i < 4; ++i){
    int idx = t + i*256;
    int row = idx >> 4, c8 = idx & 15;
    pw[i] = *(const uint4*)(wt + (size_t)row*256 + 128 + c8*8);
  }

  f32x4 acc[4];
  #pragma unroll
  for (int cb = 0; cb < 4; ++cb) acc[cb] = (f32x4){0.f,0.f,0.f,0.f};

  // ---- MFMA on chunk 0 ----
  #pragma unroll
  for (int ks = 0; ks < 4; ++ks){
    short8 a = *(const short8*)&xs[wv*16 + fr][ks*32 + fq*8];
    #pragma unroll
    for (int cb = 0; cb < 4; ++cb){
      short8 b = *(const short8*)&ws[cb*16 + fr][ks*32 + fq*8];
      acc[cb] = __builtin_amdgcn_mfma_f32_16x16x32_bf16(a, b, acc[cb], 0, 0, 0);
    }
  }
  __syncthreads();

  // ---- write prefetched chunk 1 from registers to LDS ----
  #pragma unroll
  for (int i = 0; i < 8; ++i){
    int idx = t + i*256;
    int row = idx >> 5, c4 = idx & 31;
    uint2 p;
    p.x = f2bf(px[i].x) | (f2bf(px[i].y) << 16);
    p.y = f2bf(px[i].z) | (f2bf(px[i].w) << 16);
    *(uint2*)&xs[row][c4*4] = p;
  }
  #pragma unroll
  for (int i = 0; i < 4; ++i){
    int idx = t + i*256;
    int row = idx >> 4, c8 = idx & 15;
    *(uint4*)&ws[row][c8*8] = pw[i];
  }
  __syncthreads();

  // ---- MFMA on chunk 1 ----
  #pragma unroll
  for (int ks = 0; ks < 4; ++ks){
    short8 a = *(const short8*)&xs[wv*16 + fr][ks*32 + fq*8];
    #pragma unroll
    for (int cb = 0; cb < 4; ++cb){
      short8 b = *(const short8*)&ws[cb*16 + fr][ks*32 + fq*8];
      acc[cb] = __builtin_amdgcn_mfma_f32_16x16x32_bf16(a, b, acc[cb], 0, 0, 0);
    }
  }
  __syncthreads();                       // xs dead; hs takes over

  #pragma unroll
  for (int cb = 0; cb < 4; ++cb)
    #pragma unroll
    for (int r = 0; r < 4; ++r)
      hs[wv*16 + fq*4 + r][cb*16 + fr] = (ushort)f2bf(acc[cb][r]);
  __syncthreads();
  #pragma unroll
  for (int p = 0; p < 2; ++p){
    int pid = t + p*256;
    int row = pid >> 3, hd = pid & 7;
    if (rb + row < n){
      uint4 u = *(const uint4*)&hs[row][hd*8];
      float v0=bflo(u.x), v1=bfhi(u.x), v2=bflo(u.y), v3=bfhi(u.y);
      float v4=bflo(u.z), v5=bfhi(u.z), v6=bflo(u.w), v7=bfhi(u.w);
      const float* sa = atts + hd*8;
      const float* da = attd + hd*8;
      float ds = v0*sa[0]+v1*sa[1]+v2*sa[2]+v3*sa[3]+v4*sa[4]+v5*sa[5]+v6*sa[6]+v7*sa[7];
      float dd = v0*da[0]+v1*da[1]+v2*da[2]+v3*da[3]+v4*da[4]+v5*da[5]+v6*da[6]+v7*da[7];
      as1[(size_t)(rb+row)*L_H1 + hd] = ds;
      ad1[(size_t)(rb+row)*L_H1 + hd] = dd;
    }
  }
  #pragma unroll
  for (int i = 0; i < 2; ++i){
    int idx = t + i*256;
    int row = idx >> 3, c8 = idx & 7;
    if (rb + row < n)
      *(uint4*)(h1b + (size_t)(rb+row)*L_C1 + c8*8) = *(const uint4*)&hs[row][c8*8];
  }
}

// ---------------- bucket_csr: 512 threads (stage/scatter on 8 waves) ----------------
__global__ __launch_bounds__(512) void bucket_csr(const unsigned* __restrict__ binned,
    const int* __restrict__ gcur, int2* __restrict__ nodeptr, int* __restrict__ csr,
    int N){
  __shared__ unsigned ebuf[BCAP];
  __shared__ int cnt[256], pref[256], cur[256];
  const int t = threadIdx.x;
  const int b = blockIdx.x;
  int ne = gcur[b]; if (ne > BCAP) ne = BCAP;
  const int base = b * BCAP;
  if (t < 256){ cnt[t] = 0; cur[t] = 0; }
  __syncthreads();
  for (int i = t; i < ne; i += 512){
    unsigned e = binned[base + i];
    ebuf[i] = e;
    atomicAdd(&cnt[(e >> 17) & 255u], 1);
  }
  __syncthreads();
  if (t < 256) pref[t] = cnt[t];
  __syncthreads();
  for (int off = 1; off < 256; off <<= 1){
    int a = 0;
    if (t < 256 && t >= off) a = pref[t-off];
    __syncthreads();
    if (t < 256) pref[t] += a;
    __syncthreads();
  }
  int excl = 0;
  if (t < 256) excl = pref[t] - cnt[t];
  __syncthreads();
  if (t < 256){
    pref[t] = excl;
    int d = (b << 8) + t;
    if (d < N) nodeptr[d] = make_int2(base + excl, cnt[t]);
  }
  __syncthreads();
  for (int i = t; i < ne; i += 512){
    unsigned e = ebuf[i];
    int ln = (int)((e >> 17) & 255u);
    int pos = base + pref[ln] + atomicAdd(&cur[ln], 1);
    csr[pos] = (int)(e & 0x1FFFFu);
  }
}

// ---------------- AGG1: single-pass softmax-aggregate + bias + relu (bf16 out) ----------------
__global__ __launch_bounds__(256) void agg1_kernel(
    const int2* __restrict__ nodeptr, const int* __restrict__ csr,
    const ushort* __restrict__ h1b, const float* __restrict__ as1,
    const float* __restrict__ ad1, const float* __restrict__ b1,
    ushort* __restrict__ hrb, int n)
{
  int wid  = (blockIdx.x*blockDim.x + threadIdx.x) >> 6;
  int lane = threadIdx.x & 63;
  if (wid >= n) return;
  int2 np  = nodeptr[wid];
  int beg  = np.x;
  int degt = np.y + 1;                    // + virtual self-loop

  const int h  = lane & 7;    // head (weight layout)
  const int eg = lane >> 3;   // edge-in-group (weight layout)
  const int cp = lane & 31;   // channel pair (acc layout)
  const int ep = lane >> 5;   // edge parity (acc layout)
  const int hc = cp >> 2;     // this lane's head in acc layout

  float adn = ad1[(size_t)wid*L_H1 + h];
  float ax = 0.f, ay = 0.f, sp = 0.f;

  #define A1_GRP_W(g, SRCV, WV)                                            \
    { int i_ = (g)*8 + eg;                                                 \
      SRCV = (i_ < degt-1) ? csr[beg + i_] : wid;                          \
      float l_ = (i_ < degt) ? leaky(as1[(size_t)SRCV*L_H1 + h] + adn)     \
                             : -1e30f;                                     \
      WV = __expf(l_); sp += WV; }
  #define A1_GRP_G(SRCV, WV)                                               \
    _Pragma("unroll")                                                      \
    for (int e0 = 0; e0 < 8; e0 += 2){                                     \
      int e_  = e0 + ep;                                                   \
      float we_ = __shfl(WV,   e_*8 + hc);                                 \
      int   se_ = __shfl(SRCV, e_*8);                                      \
      unsigned u_ = *(const unsigned*)(h1b + (size_t)se_*L_C1 + cp*2);     \
      ax += we_ * bflo(u_);                                                \
      ay += we_ * bfhi(u_);                                                \
    }

  if (degt <= 16){
    int s0, s1; float w0, w1;
    A1_GRP_W(0, s0, w0) A1_GRP_W(1, s1, w1)
    A1_GRP_G(s0, w0) A1_GRP_G(s1, w1)
  } else if (degt <= 24){
    int s0, s1, s2; float w0, w1, w2;
    A1_GRP_W(0, s0, w0) A1_GRP_W(1, s1, w1) A1_GRP_W(2, s2, w2)
    A1_GRP_G(s0, w0) A1_GRP_G(s1, w1) A1_GRP_G(s2, w2)
  } else {
    const int ngrp = (degt + 7) >> 3;
    for (int g = 0; g < ngrp; ++g){
      int sg; float wg;
      A1_GRP_W(g, sg, wg)
      A1_GRP_G(sg, wg)
    }
  }
  #undef A1_GRP_W
  #undef A1_GRP_G

  #pragma unroll
  for (int off = 8; off < 64; off <<= 1) sp += __shfl_xor(sp, off);
  float rinv = 1.0f / __shfl(sp, hc);
  ax += __shfl_xor(ax, 32);
  ay += __shfl_xor(ay, 32);
  if (lane < 32){
    float2 bv = *(const float2*)&b1[cp*2];
    float r0 = fmaxf(ax*rinv + bv.x, 0.f);
    float r1 = fmaxf(ay*rinv + bv.y, 0.f);
    *(unsigned*)(hrb + (size_t)wid*L_C1 + cp*2) = f2bf(r0) | (f2bf(r1) << 16);
  }
}

// ---------------- GEMM2: h2 = hrelu @ W2 (+att dots), reg-resident rows ----------------
__global__ __launch_bounds__(256) void gemm2_kernel(
    const ushort* __restrict__ hrb, const float* __restrict__ W2,
    const float* __restrict__ atts2, const float* __restrict__ attd2,
    ushort* __restrict__ h2b, float* __restrict__ as2, float* __restrict__ ad2, int n)
{
  __shared__ float w2s[64*40];
  const int t = threadIdx.x;
  for (int i = t; i < 64*40; i += 256) w2s[i] = W2[i];
  __syncthreads();
  int row = blockIdx.x*256 + t;
  if (row >= n) return;

  uint4 rv[8];
  #pragma unroll
  for (int q = 0; q < 8; ++q)
    rv[q] = *(const uint4*)(hrb + (size_t)row*L_C1 + q*8);

  f32x4 acc4[10];
  #pragma unroll
  for (int j = 0; j < 10; ++j) acc4[j] = (f32x4){0.f,0.f,0.f,0.f};

  #pragma unroll
  for (int q = 0; q < 8; ++q){
    unsigned uu[4] = {rv[q].x, rv[q].y, rv[q].z, rv[q].w};
    #pragma unroll
    for (int d = 0; d < 4; ++d){
      int k = q*8 + d*2;
      float v0 = bflo(uu[d]), v1 = bfhi(uu[d]);
      const f32x4* w0 = (const f32x4*)&w2s[k*40];
      const f32x4* w1 = (const f32x4*)&w2s[(k+1)*40];
      #pragma unroll
      for (int j = 0; j < 10; ++j) acc4[j] += v0*w0[j] + v1*w1[j];
    }
  }

  float acc[40];
  #pragma unroll
  for (int j = 0; j < 10; ++j){
    acc[4*j+0]=acc4[j][0]; acc[4*j+1]=acc4[j][1];
    acc[4*j+2]=acc4[j][2]; acc[4*j+3]=acc4[j][3];
  }
  float ps = 0.f, pd = 0.f;
  #pragma unroll
  for (int j = 0; j < 40; ++j){ ps += acc[j]*atts2[j]; pd += acc[j]*attd2[j]; }
  unsigned pk[20];
  #pragma unroll
  for (int q = 0; q < 20; ++q) pk[q] = f2bf(acc[2*q]) | (f2bf(acc[2*q+1]) << 16);
  uint4* dst = (uint4*)(h2b + (size_t)row*L_OUT);
  #pragma unroll
  for (int q = 0; q < 5; ++q) dst[q] = make_uint4(pk[4*q],pk[4*q+1],pk[4*q+2],pk[4*q+3]);
  as2[row] = ps;
  ad2[row] = pd;
}

// ---------------- AGG2 + bias + log_softmax: 3-edge x 20-chpair, tiered ----------------
__global__ __launch_bounds__(256) void agg2_kernel(
    const int2* __restrict__ nodeptr, const int* __restrict__ csr,
    const ushort* __restrict__ h2b, const float* __restrict__ as2,
    const float* __restrict__ ad2, const float* __restrict__ b2,
    float* __restrict__ out, int n)
{
  int wid  = (blockIdx.x*blockDim.x + threadIdx.x) >> 6;
  int lane = threadIdx.x & 63;
  if (wid >= n) return;
  int2 np  = nodeptr[wid];
  int beg  = np.x;
  int degt = np.y + 1;

  const int eidx = (lane < 60) ? (lane / 20) : 0;   // edge-in-step (0..2)
  const int cq   = (lane < 60) ? (lane % 20) : 0;   // channel pair (0..19)

  float adn = ad2[wid];
  float ax = 0.f, ay = 0.f, sp = 0.f;

  #define A2_STEP(e_, SRCV, WV, CNT)                                       \
    { int ee_ = (e_);                                                      \
      int es_ = (ee_ < 64) ? ee_ : 63;                                     \
      float we_ = __shfl(WV,   es_);                                       \
      int   se_ = __shfl(SRCV, es_);                                       \
      we_ = (ee_ < (CNT)) ? we_ : 0.f;                                     \
      unsigned u_ = *(const unsigned*)(h2b + (size_t)se_*L_OUT + cq*2);    \
      ax += we_ * bflo(u_);                                                \
      ay += we_ * bfhi(u_); }

  if (degt <= 64){
    int i = lane;
    int src = (i < degt-1) ? csr[beg + i] : wid;
    float l = (i < degt) ? leaky(as2[src] + adn) : -1e30f;
    float w = __expf(l);
    sp = w;
    if (degt <= 18){
      #pragma unroll
      for (int j = 0; j < 2; ++j){
        A2_STEP(j*9 + 0*3 + eidx, src, w, degt)
        A2_STEP(j*9 + 1*3 + eidx, src, w, degt)
        A2_STEP(j*9 + 2*3 + eidx, src, w, degt)
      }
    } else if (degt <= 27){
      #pragma unroll
      for (int j = 0; j < 3; ++j){
        A2_STEP(j*9 + 0*3 + eidx, src, w, degt)
        A2_STEP(j*9 + 1*3 + eidx, src, w, degt)
        A2_STEP(j*9 + 2*3 + eidx, src, w, degt)
      }
    } else if (degt <= 36){
      #pragma unroll
      for (int j = 0; j < 4; ++j){
        A2_STEP(j*9 + 0*3 + eidx, src, w, degt)
        A2_STEP(j*9 + 1*3 + eidx, src, w, degt)
        A2_STEP(j*9 + 2*3 + eidx, src, w, degt)
      }
    } else {
      for (int e0 = 0; e0 < degt; e0 += 9){
        A2_STEP(e0 + 0*3 + eidx, src, w, degt)
        A2_STEP(e0 + 1*3 + eidx, src, w, degt)
        A2_STEP(e0 + 2*3 + eidx, src, w, degt)
      }
    }
  } else {
    const int ngrp = (degt + 63) >> 6;
    for (int g = 0; g < ngrp; ++g){
      int i = g*64 + lane;
      int src = (i < degt-1) ? csr[beg + i] : wid;
      float l = (i < degt) ? leaky(as2[src] + adn) : -1e30f;
      float w = __expf(l);
      sp += w;
      int cnt = degt - g*64; if (cnt > 64) cnt = 64;
      for (int e0 = 0; e0 < cnt; e0 += 9){
        A2_STEP(e0 + 0*3 + eidx, src, w, cnt)
        A2_STEP(e0 + 1*3 + eidx, src, w, cnt)
        A2_STEP(e0 + 2*3 + eidx, src, w, cnt)
      }
    }
  }
  #undef A2_STEP

  #pragma unroll
  for (int off = 1; off < 64; off <<= 1) sp += __shfl_xor(sp, off);
  float rinv = 1.0f / sp;

  // cross-eidx reduction: channel cq lives in lanes {cq, cq+20, cq+40}
  float ax0 = __shfl(ax, cq), ax1 = __shfl(ax, cq+20), ax2 = __shfl(ax, cq+40);
  float ay0 = __shfl(ay, cq), ay1 = __shfl(ay, cq+20), ay2 = __shfl(ay, cq+40);
  float axs = (ax0 + ax1) + ax2;
  float ays = (ay0 + ay1) + ay2;

  bool act = (lane < 20);
  float o0 = axs*rinv + b2[cq*2];
  float o1 = ays*rinv + b2[cq*2+1];
  float mx = act ? fmaxf(o0, o1) : -1e30f;
  #pragma unroll
  for (int off = 1; off < 32; off <<= 1) mx = fmaxf(mx, __shfl_xor(mx, off));
  float ex = act ? (__expf(o0 - mx) + __expf(o1 - mx)) : 0.f;
  #pragma unroll
  for (int off = 1; off < 32; off <<= 1) ex += __shfl_xor(ex, off);
  float lse = mx + __logf(ex);
  if (act){
    float2 r = make_float2(o0 - lse, o1 - lse);
    *(float2*)(out + (size_t)wid*L_OUT + cq*2) = r;
  }
}

// ---------------- launch ----------------
extern "C" void kernel_launch(void* const* d_in, const int* in_sizes, int n_in,
                              void* d_out, int out_size, void* d_ws, size_t ws_size,
                              hipStream_t stream)
{
  const float* x    = (const float*)d_in[0];
  const int*   ei   = (const int*)  d_in[1];
  const float* W1   = (const float*)d_in[2];
  const float* as1w = (const float*)d_in[3];
  const float* ad1w = (const float*)d_in[4];
  const float* b1   = (const float*)d_in[5];
  const float* W2   = (const float*)d_in[6];
  const float* as2w = (const float*)d_in[7];
  const float* ad2w = (const float*)d_in[8];
  const float* b2   = (const float*)d_in[9];

  const int N = in_sizes[0] / L_IN;
  const int E = in_sizes[1] / 2;
  const int NB = (N + 255) >> 8;          // buckets of 256 nodes (<=512)
  const int NSC = (E + 4095) / 4096;      // scatter blocks
  const int* esrc = ei;
  const int* edst = ei + E;
  float* out = (float*)d_out;

  char* w = (char*)d_ws;
  auto alloc = [&](size_t bytes)->char*{
    char* p = w; w += (bytes + 255) & ~size_t(255); return p;
  };
  ushort* h1b  = (ushort*)alloc((size_t)N*L_C1*2);
  float*  as1  = (float*) alloc((size_t)N*L_H1*4);
  float*  ad1  = (float*) alloc((size_t)N*L_H1*4);
  // union: binned (NB*BCAP*4, dead after bucket_csr) aliases hrb+h2b
  size_t union_sz = (size_t)N*L_C1*2 + (size_t)N*L_OUT*2;
  if (union_sz < (size_t)NB*BCAP*4) union_sz = (size_t)NB*BCAP*4;
  char*  ub    = alloc(union_sz);
  ushort* hrb  = (ushort*)ub;
  ushort* h2b  = (ushort*)(ub + (size_t)N*L_C1*2);
  unsigned* binned = (unsigned*)ub;
  float*  as2  = (float*) alloc((size_t)N*4);
  float*  ad2  = (float*) alloc((size_t)N*4);
  ushort* wt   = (ushort*)alloc((size_t)64*256*2);
  int2*  nodeptr=(int2*)  alloc((size_t)N*8);
  int*   csr   = (int*)   alloc((size_t)NB*BCAP*4);
  int*   gcur  = (int*)   alloc((size_t)NB*4);

  prep_w1     <<<5,          256, 0, stream>>>(W1, wt, gcur, NB);
  bin_scatter <<<NSC,        256, 0, stream>>>(esrc, edst, gcur, binned, E, NB);
  gemm1_kernel<<<(N+63)/64,  256, 0, stream>>>(x, wt, as1w, ad1w, h1b, as1, ad1, N);
  bucket_csr  <<<NB,         512, 0, stream>>>(binned, gcur, nodeptr, csr, N);
  agg1_kernel <<<(N+3)/4,    256, 0, stream>>>(nodeptr, csr, h1b, as1, ad1, b1, hrb, N);
  gemm2_kernel<<<(N+255)/256,256, 0, stream>>>(hrb, W2, as2w, ad2w, h2b, as2, ad2, N);
  agg2_kernel <<<(N+3)/4,    256, 0, stream>>>(nodeptr, csr, h2b, as2, ad2, b2, out, N);
}

// Round 15
// 183.814 us; speedup vs baseline: 1.0377x; 1.0092x over previous
//
#include <hip/hip_runtime.h>

// GAT 2-layer: N=100000, IN=256, L1: heads=8 x 8, L2: heads=1 x 40.
// R15: barrier-free persistent gemm1. R14 showed gemm1 = 58us with VALUBusy
// 9.5% / occupancy 30% -- 1563 one-shot blocks each serializing 5 barriers
// against HBM latency. New: stage full wt once (1 barrier/kernel), A-frags
// loaded global->reg (wave owns its 16 rows), epilogue through a wave-private
// hs slice (DS ops in-wave are ordered -> NO per-tile barriers), persistent
// grid 768 (3 blocks/CU @ 43KB LDS). All other kernels unchanged from R14.

#define L_IN   256
#define L_C1   64
#define L_H1   8
#define L_OUT  40
#define BCAP   5120     // bucket capacity (mean 4092, sigma ~64)

typedef __attribute__((ext_vector_type(8))) short short8;
typedef __attribute__((ext_vector_type(4))) float f32x4;

__device__ __forceinline__ float leaky(float x){ return fmaxf(x, 0.2f*x); }
__device__ __forceinline__ unsigned f2bf(float f){
  unsigned u = __float_as_uint(f);
  return (u + 0x7fffu + ((u >> 16) & 1u)) >> 16;     // RNE
}
__device__ __forceinline__ float bflo(unsigned u){ return __uint_as_float(u << 16); }
__device__ __forceinline__ float bfhi(unsigned u){ return __uint_as_float(u & 0xffff0000u); }

// ---------------- prep: W1 -> wt (bf16 transposed); block 4 zeros gcur ----------------
__global__ __launch_bounds__(256) void prep_w1(const float* __restrict__ W1,
                                               ushort* __restrict__ wt,
                                               int* __restrict__ gcur, int NB){
  const int t = threadIdx.x;
  if (blockIdx.x == 4){
    for (int i = t; i < NB; i += 256) gcur[i] = 0;
    return;
  }
  __shared__ float ws[64][65];
  const int kb = blockIdx.x;            // 4 blocks, one K-chunk each
  #pragma unroll
  for (int i = 0; i < 16; ++i){
    int idx = t + i*256;
    ws[idx >> 6][idx & 63] = W1[(size_t)(kb*64 + (idx >> 6))*64 + (idx & 63)];
  }
  __syncthreads();
  int c  = t >> 2;
  int j0 = (t & 3) * 16;
  ushort tmp[16];
  #pragma unroll
  for (int j = 0; j < 16; ++j) tmp[j] = (ushort)f2bf(ws[j0 + j][c]);
  uint4* dst = (uint4*)(wt + (size_t)c*256 + kb*64 + j0);
  dst[0] = *(uint4*)&tmp[0];
  dst[1] = *(uint4*)&tmp[8];
}

// ---------------- bin_scatter: standalone (6KB LDS -> 8 blocks/CU) ----------------
// Entry = src | (local_dst << 17)  [N < 131072].
__global__ __launch_bounds__(256) void bin_scatter(const int* __restrict__ esrc,
    const int* __restrict__ edst, int* __restrict__ gcur,
    unsigned* __restrict__ binned, int E, int NB){
  __shared__ int hist[512], rbase[512], cur[512];
  const int t  = threadIdx.x;
  const int e0 = blockIdx.x * 4096;
  hist[t] = 0; hist[t+256] = 0; cur[t] = 0; cur[t+256] = 0;
  __syncthreads();
  int sv[16], dv[16];
  const bool full = (e0 + 4096 <= E);
  if (full){
    #pragma unroll
    for (int j = 0; j < 4; ++j){
      int p4 = (e0 >> 2) + j*256 + t;
      int4 s4 = ((const int4*)esrc)[p4];
      int4 d4 = ((const int4*)edst)[p4];
      sv[4*j+0]=s4.x; sv[4*j+1]=s4.y; sv[4*j+2]=s4.z; sv[4*j+3]=s4.w;
      dv[4*j+0]=d4.x; dv[4*j+1]=d4.y; dv[4*j+2]=d4.z; dv[4*j+3]=d4.w;
      atomicAdd(&hist[d4.x >> 8], 1); atomicAdd(&hist[d4.y >> 8], 1);
      atomicAdd(&hist[d4.z >> 8], 1); atomicAdd(&hist[d4.w >> 8], 1);
    }
  } else {
    #pragma unroll
    for (int j = 0; j < 16; ++j){
      int idx = e0 + j*256 + t;
      if (idx < E){
        sv[j] = esrc[idx]; dv[j] = edst[idx];
        atomicAdd(&hist[dv[j] >> 8], 1);
      } else dv[j] = -1;
    }
  }
  __syncthreads();
  if (hist[t])                   rbase[t]     = atomicAdd(&gcur[t],     hist[t]);
  if (t+256 < NB && hist[t+256]) rbase[t+256] = atomicAdd(&gcur[t+256], hist[t+256]);
  __syncthreads();
  #pragma unroll
  for (int j = 0; j < 16; ++j){
    if (dv[j] >= 0){
      int b = dv[j] >> 8;
      int off = rbase[b] + atomicAdd(&cur[b], 1);
      if (off < BCAP)
        binned[(size_t)b*BCAP + off] =
          (unsigned)sv[j] | ((unsigned)(dv[j] & 255) << 17);
    }
  }
}

// ---------------- GEMM1: persistent, barrier-free tiles ----------------
__global__ __launch_bounds__(256) void gemm1_kernel(
    const float* __restrict__ x, const ushort* __restrict__ wt,
    const float* __restrict__ atts, const float* __restrict__ attd,
    ushort* __restrict__ h1b, float* __restrict__ as1, float* __restrict__ ad1,
    int n, int ntiles, int npb)
{
  __shared__ ushort ws[64][264];        // full wt (64 cols x 256 k), pad 8
  __shared__ ushort hs[64][72];         // wave-private 16-row slices
  const int t  = threadIdx.x;
  const int wv = t >> 6;
  const int ln = t & 63;
  const int fr = ln & 15;
  const int fq = ln >> 4;

  // stage full wt once (2048 uint4)
  #pragma unroll
  for (int i = 0; i < 8; ++i){
    int idx = t + i*256;
    int row = idx >> 5, c8 = idx & 31;
    *(uint4*)&ws[row][c8*8] = *(const uint4*)(wt + (size_t)row*256 + c8*8);
  }
  __syncthreads();                      // the ONLY barrier

  for (int tile = blockIdx.x; tile < ntiles; tile += npb){
    const int rb = tile * 64;
    const int ar = rb + wv*16 + fr;     // this lane's A row
    const bool rv = ar < n;
    const float* xr = x + (size_t)(rv ? ar : 0) * L_IN;

    f32x4 acc[4];
    #pragma unroll
    for (int cb = 0; cb < 4; ++cb) acc[cb] = (f32x4){0.f,0.f,0.f,0.f};

    #pragma unroll
    for (int kk = 0; kk < 8; ++kk){
      const int k0 = kk*32 + fq*8;
      float4 a0 = make_float4(0.f,0.f,0.f,0.f), a1 = a0;
      if (rv){
        a0 = *(const float4*)(xr + k0);
        a1 = *(const float4*)(xr + k0 + 4);
      }
      uint4 au;
      au.x = f2bf(a0.x) | (f2bf(a0.y) << 16);
      au.y = f2bf(a0.z) | (f2bf(a0.w) << 16);
      au.z = f2bf(a1.x) | (f2bf(a1.y) << 16);
      au.w = f2bf(a1.z) | (f2bf(a1.w) << 16);
      short8 a = *(short8*)&au;
      #pragma unroll
      for (int cb = 0; cb < 4; ++cb){
        short8 b = *(const short8*)&ws[cb*16 + fr][k0];
        acc[cb] = __builtin_amdgcn_mfma_f32_16x16x32_bf16(a, b, acc[cb], 0, 0, 0);
      }
    }

    // epilogue: C frags -> wave-private hs slice (in-wave DS ordering, no barrier)
    #pragma unroll
    for (int cb = 0; cb < 4; ++cb)
      #pragma unroll
      for (int r = 0; r < 4; ++r)
        hs[wv*16 + fq*4 + r][cb*16 + fr] = (ushort)f2bf(acc[cb][r]);

    #pragma unroll
    for (int i = 0; i < 2; ++i){
      int task = ln + i*64;             // 128 tasks per wave
      int lrow = task >> 3;             // 0..15
      int sub  = task & 7;              // head AND uint4-group
      int row  = rb + wv*16 + lrow;
      if (row < n){
        uint4 u = *(const uint4*)&hs[wv*16 + lrow][sub*8];
        *(uint4*)(h1b + (size_t)row*L_C1 + sub*8) = u;
        float v0=bflo(u.x), v1=bfhi(u.x), v2=bflo(u.y), v3=bfhi(u.y);
        float v4=bflo(u.z), v5=bfhi(u.z), v6=bflo(u.w), v7=bfhi(u.w);
        const float* sa = atts + sub*8;
        const float* da = attd + sub*8;
        float ds = v0*sa[0]+v1*sa[1]+v2*sa[2]+v3*sa[3]+v4*sa[4]+v5*sa[5]+v6*sa[6]+v7*sa[7];
        float dd = v0*da[0]+v1*da[1]+v2*da[2]+v3*da[3]+v4*da[4]+v5*da[5]+v6*da[6]+v7*da[7];
        as1[(size_t)row*L_H1 + sub] = ds;
        ad1[(size_t)row*L_H1 + sub] = dd;
      }
    }
  }
}

// ---------------- bucket_csr: 512 threads (stage/scatter on 8 waves) ----------------
__global__ __launch_bounds__(512) void bucket_csr(const unsigned* __restrict__ binned,
    const int* __restrict__ gcur, int2* __restrict__ nodeptr, int* __restrict__ csr,
    int N){
  __shared__ unsigned ebuf[BCAP];
  __shared__ int cnt[256], pref[256], cur[256];
  const int t = threadIdx.x;
  const int b = blockIdx.x;
  int ne = gcur[b]; if (ne > BCAP) ne = BCAP;
  const int base = b * BCAP;
  if (t < 256){ cnt[t] = 0; cur[t] = 0; }
  __syncthreads();
  for (int i = t; i < ne; i += 512){
    unsigned e = binned[base + i];
    ebuf[i] = e;
    atomicAdd(&cnt[(e >> 17) & 255u], 1);
  }
  __syncthreads();
  if (t < 256) pref[t] = cnt[t];
  __syncthreads();
  for (int off = 1; off < 256; off <<= 1){
    int a = 0;
    if (t < 256 && t >= off) a = pref[t-off];
    __syncthreads();
    if (t < 256) pref[t] += a;
    __syncthreads();
  }
  int excl = 0;
  if (t < 256) excl = pref[t] - cnt[t];
  __syncthreads();
  if (t < 256){
    pref[t] = excl;
    int d = (b << 8) + t;
    if (d < N) nodeptr[d] = make_int2(base + excl, cnt[t]);
  }
  __syncthreads();
  for (int i = t; i < ne; i += 512){
    unsigned e = ebuf[i];
    int ln = (int)((e >> 17) & 255u);
    int pos = base + pref[ln] + atomicAdd(&cur[ln], 1);
    csr[pos] = (int)(e & 0x1FFFFu);
  }
}

// ---------------- AGG1: single-pass softmax-aggregate + bias + relu (bf16 out) ----------------
__global__ __launch_bounds__(256) void agg1_kernel(
    const int2* __restrict__ nodeptr, const int* __restrict__ csr,
    const ushort* __restrict__ h1b, const float* __restrict__ as1,
    const float* __restrict__ ad1, const float* __restrict__ b1,
    ushort* __restrict__ hrb, int n)
{
  int wid  = (blockIdx.x*blockDim.x + threadIdx.x) >> 6;
  int lane = threadIdx.x & 63;
  if (wid >= n) return;
  int2 np  = nodeptr[wid];
  int beg  = np.x;
  int degt = np.y + 1;                    // + virtual self-loop

  const int h  = lane & 7;    // head (weight layout)
  const int eg = lane >> 3;   // edge-in-group (weight layout)
  const int cp = lane & 31;   // channel pair (acc layout)
  const int ep = lane >> 5;   // edge parity (acc layout)
  const int hc = cp >> 2;     // this lane's head in acc layout

  float adn = ad1[(size_t)wid*L_H1 + h];
  float ax = 0.f, ay = 0.f, sp = 0.f;

  #define A1_GRP_W(g, SRCV, WV)                                            \
    { int i_ = (g)*8 + eg;                                                 \
      SRCV = (i_ < degt-1) ? csr[beg + i_] : wid;                          \
      float l_ = (i_ < degt) ? leaky(as1[(size_t)SRCV*L_H1 + h] + adn)     \
                             : -1e30f;                                     \
      WV = __expf(l_); sp += WV; }
  #define A1_GRP_G(SRCV, WV)                                               \
    _Pragma("unroll")                                                      \
    for (int e0 = 0; e0 < 8; e0 += 2){                                     \
      int e_  = e0 + ep;                                                   \
      float we_ = __shfl(WV,   e_*8 + hc);                                 \
      int   se_ = __shfl(SRCV, e_*8);                                      \
      unsigned u_ = *(const unsigned*)(h1b + (size_t)se_*L_C1 + cp*2);     \
      ax += we_ * bflo(u_);                                                \
      ay += we_ * bfhi(u_);                                                \
    }

  if (degt <= 16){
    int s0, s1; float w0, w1;
    A1_GRP_W(0, s0, w0) A1_GRP_W(1, s1, w1)
    A1_GRP_G(s0, w0) A1_GRP_G(s1, w1)
  } else if (degt <= 24){
    int s0, s1, s2; float w0, w1, w2;
    A1_GRP_W(0, s0, w0) A1_GRP_W(1, s1, w1) A1_GRP_W(2, s2, w2)
    A1_GRP_G(s0, w0) A1_GRP_G(s1, w1) A1_GRP_G(s2, w2)
  } else {
    const int ngrp = (degt + 7) >> 3;
    for (int g = 0; g < ngrp; ++g){
      int sg; float wg;
      A1_GRP_W(g, sg, wg)
      A1_GRP_G(sg, wg)
    }
  }
  #undef A1_GRP_W
  #undef A1_GRP_G

  #pragma unroll
  for (int off = 8; off < 64; off <<= 1) sp += __shfl_xor(sp, off);
  float rinv = 1.0f / __shfl(sp, hc);
  ax += __shfl_xor(ax, 32);
  ay += __shfl_xor(ay, 32);
  if (lane < 32){
    float2 bv = *(const float2*)&b1[cp*2];
    float r0 = fmaxf(ax*rinv + bv.x, 0.f);
    float r1 = fmaxf(ay*rinv + bv.y, 0.f);
    *(unsigned*)(hrb + (size_t)wid*L_C1 + cp*2) = f2bf(r0) | (f2bf(r1) << 16);
  }
}

// ---------------- GEMM2: h2 = hrelu @ W2 (+att dots), reg-resident rows ----------------
__global__ __launch_bounds__(256) void gemm2_kernel(
    const ushort* __restrict__ hrb, const float* __restrict__ W2,
    const float* __restrict__ atts2, const float* __restrict__ attd2,
    ushort* __restrict__ h2b, float* __restrict__ as2, float* __restrict__ ad2, int n)
{
  __shared__ float w2s[64*40];
  const int t = threadIdx.x;
  for (int i = t; i < 64*40; i += 256) w2s[i] = W2[i];
  __syncthreads();
  int row = blockIdx.x*256 + t;
  if (row >= n) return;

  uint4 rv[8];
  #pragma unroll
  for (int q = 0; q < 8; ++q)
    rv[q] = *(const uint4*)(hrb + (size_t)row*L_C1 + q*8);

  f32x4 acc4[10];
  #pragma unroll
  for (int j = 0; j < 10; ++j) acc4[j] = (f32x4){0.f,0.f,0.f,0.f};

  #pragma unroll
  for (int q = 0; q < 8; ++q){
    unsigned uu[4] = {rv[q].x, rv[q].y, rv[q].z, rv[q].w};
    #pragma unroll
    for (int d = 0; d < 4; ++d){
      int k = q*8 + d*2;
      float v0 = bflo(uu[d]), v1 = bfhi(uu[d]);
      const f32x4* w0 = (const f32x4*)&w2s[k*40];
      const f32x4* w1 = (const f32x4*)&w2s[(k+1)*40];
      #pragma unroll
      for (int j = 0; j < 10; ++j) acc4[j] += v0*w0[j] + v1*w1[j];
    }
  }

  float acc[40];
  #pragma unroll
  for (int j = 0; j < 10; ++j){
    acc[4*j+0]=acc4[j][0]; acc[4*j+1]=acc4[j][1];
    acc[4*j+2]=acc4[j][2]; acc[4*j+3]=acc4[j][3];
  }
  float ps = 0.f, pd = 0.f;
  #pragma unroll
  for (int j = 0; j < 40; ++j){ ps += acc[j]*atts2[j]; pd += acc[j]*attd2[j]; }
  unsigned pk[20];
  #pragma unroll
  for (int q = 0; q < 20; ++q) pk[q] = f2bf(acc[2*q]) | (f2bf(acc[2*q+1]) << 16);
  uint4* dst = (uint4*)(h2b + (size_t)row*L_OUT);
  #pragma unroll
  for (int q = 0; q < 5; ++q) dst[q] = make_uint4(pk[4*q],pk[4*q+1],pk[4*q+2],pk[4*q+3]);
  as2[row] = ps;
  ad2[row] = pd;
}

// ---------------- AGG2 + bias + log_softmax: 3-edge x 20-chpair, tiered ----------------
__global__ __launch_bounds__(256) void agg2_kernel(
    const int2* __restrict__ nodeptr, const int* __restrict__ csr,
    const ushort* __restrict__ h2b, const float* __restrict__ as2,
    const float* __restrict__ ad2, const float* __restrict__ b2,
    float* __restrict__ out, int n)
{
  int wid  = (blockIdx.x*blockDim.x + threadIdx.x) >> 6;
  int lane = threadIdx.x & 63;
  if (wid >= n) return;
  int2 np  = nodeptr[wid];
  int beg  = np.x;
  int degt = np.y + 1;

  const int eidx = (lane < 60) ? (lane / 20) : 0;   // edge-in-step (0..2)
  const int cq   = (lane < 60) ? (lane % 20) : 0;   // channel pair (0..19)

  float adn = ad2[wid];
  float ax = 0.f, ay = 0.f, sp = 0.f;

  #define A2_STEP(e_, SRCV, WV, CNT)                                       \
    { int ee_ = (e_);                                                      \
      int es_ = (ee_ < 64) ? ee_ : 63;                                     \
      float we_ = __shfl(WV,   es_);                                       \
      int   se_ = __shfl(SRCV, es_);                                       \
      we_ = (ee_ < (CNT)) ? we_ : 0.f;                                     \
      unsigned u_ = *(const unsigned*)(h2b + (size_t)se_*L_OUT + cq*2);    \
      ax += we_ * bflo(u_);                                                \
      ay += we_ * bfhi(u_); }

  if (degt <= 64){
    int i = lane;
    int src = (i < degt-1) ? csr[beg + i] : wid;
    float l = (i < degt) ? leaky(as2[src] + adn) : -1e30f;
    float w = __expf(l);
    sp = w;
    if (degt <= 18){
      #pragma unroll
      for (int j = 0; j < 2; ++j){
        A2_STEP(j*9 + 0*3 + eidx, src, w, degt)
        A2_STEP(j*9 + 1*3 + eidx, src, w, degt)
        A2_STEP(j*9 + 2*3 + eidx, src, w, degt)
      }
    } else if (degt <= 27){
      #pragma unroll
      for (int j = 0; j < 3; ++j){
        A2_STEP(j*9 + 0*3 + eidx, src, w, degt)
        A2_STEP(j*9 + 1*3 + eidx, src, w, degt)
        A2_STEP(j*9 + 2*3 + eidx, src, w, degt)
      }
    } else if (degt <= 36){
      #pragma unroll
      for (int j = 0; j < 4; ++j){
        A2_STEP(j*9 + 0*3 + eidx, src, w, degt)
        A2_STEP(j*9 + 1*3 + eidx, src, w, degt)
        A2_STEP(j*9 + 2*3 + eidx, src, w, degt)
      }
    } else {
      for (int e0 = 0; e0 < degt; e0 += 9){
        A2_STEP(e0 + 0*3 + eidx, src, w, degt)
        A2_STEP(e0 + 1*3 + eidx, src, w, degt)
        A2_STEP(e0 + 2*3 + eidx, src, w, degt)
      }
    }
  } else {
    const int ngrp = (degt + 63) >> 6;
    for (int g = 0; g < ngrp; ++g){
      int i = g*64 + lane;
      int src = (i < degt-1) ? csr[beg + i] : wid;
      float l = (i < degt) ? leaky(as2[src] + adn) : -1e30f;
      float w = __expf(l);
      sp += w;
      int cnt = degt - g*64; if (cnt > 64) cnt = 64;
      for (int e0 = 0; e0 < cnt; e0 += 9){
        A2_STEP(e0 + 0*3 + eidx, src, w, cnt)
        A2_STEP(e0 + 1*3 + eidx, src, w, cnt)
        A2_STEP(e0 + 2*3 + eidx, src, w, cnt)
      }
    }
  }
  #undef A2_STEP

  #pragma unroll
  for (int off = 1; off < 64; off <<= 1) sp += __shfl_xor(sp, off);
  float rinv = 1.0f / sp;

  // cross-eidx reduction: channel cq lives in lanes {cq, cq+20, cq+40}
  float ax0 = __shfl(ax, cq), ax1 = __shfl(ax, cq+20), ax2 = __shfl(ax, cq+40);
  float ay0 = __shfl(ay, cq), ay1 = __shfl(ay, cq+20), ay2 = __shfl(ay, cq+40);
  float axs = (ax0 + ax1) + ax2;
  float ays = (ay0 + ay1) + ay2;

  bool act = (lane < 20);
  float o0 = axs*rinv + b2[cq*2];
  float o1 = ays*rinv + b2[cq*2+1];
  float mx = act ? fmaxf(o0, o1) : -1e30f;
  #pragma unroll
  for (int off = 1; off < 32; off <<= 1) mx = fmaxf(mx, __shfl_xor(mx, off));
  float ex = act ? (__expf(o0 - mx) + __expf(o1 - mx)) : 0.f;
  #pragma unroll
  for (int off = 1; off < 32; off <<= 1) ex += __shfl_xor(ex, off);
  float lse = mx + __logf(ex);
  if (act){
    float2 r = make_float2(o0 - lse, o1 - lse);
    *(float2*)(out + (size_t)wid*L_OUT + cq*2) = r;
  }
}

// ---------------- launch ----------------
extern "C" void kernel_launch(void* const* d_in, const int* in_sizes, int n_in,
                              void* d_out, int out_size, void* d_ws, size_t ws_size,
                              hipStream_t stream)
{
  const float* x    = (const float*)d_in[0];
  const int*   ei   = (const int*)  d_in[1];
  const float* W1   = (const float*)d_in[2];
  const float* as1w = (const float*)d_in[3];
  const float* ad1w = (const float*)d_in[4];
  const float* b1   = (const float*)d_in[5];
  const float* W2   = (const float*)d_in[6];
  const float* as2w = (const float*)d_in[7];
  const float* ad2w = (const float*)d_in[8];
  const float* b2   = (const float*)d_in[9];

  const int N = in_sizes[0] / L_IN;
  const int E = in_sizes[1] / 2;
  const int NB = (N + 255) >> 8;          // buckets of 256 nodes (<=512)
  const int NSC = (E + 4095) / 4096;      // scatter blocks
  const int NT1 = (N + 63) / 64;          // gemm1 tiles
  const int NPB = (NT1 < 768) ? NT1 : 768; // persistent gemm1 grid (3/CU)
  const int* esrc = ei;
  const int* edst = ei + E;
  float* out = (float*)d_out;

  char* w = (char*)d_ws;
  auto alloc = [&](size_t bytes)->char*{
    char* p = w; w += (bytes + 255) & ~size_t(255); return p;
  };
  ushort* h1b  = (ushort*)alloc((size_t)N*L_C1*2);
  float*  as1  = (float*) alloc((size_t)N*L_H1*4);
  float*  ad1  = (float*) alloc((size_t)N*L_H1*4);
  // union: binned (NB*BCAP*4, dead after bucket_csr) aliases hrb+h2b
  size_t union_sz = (size_t)N*L_C1*2 + (size_t)N*L_OUT*2;
  if (union_sz < (size_t)NB*BCAP*4) union_sz = (size_t)NB*BCAP*4;
  char*  ub    = alloc(union_sz);
  ushort* hrb  = (ushort*)ub;
  ushort* h2b  = (ushort*)(ub + (size_t)N*L_C1*2);
  unsigned* binned = (unsigned*)ub;
  float*  as2  = (float*) alloc((size_t)N*4);
  float*  ad2  = (float*) alloc((size_t)N*4);
  ushort* wt   = (ushort*)alloc((size_t)64*256*2);
  int2*  nodeptr=(int2*)  alloc((size_t)N*8);
  int*   csr   = (int*)   alloc((size_t)NB*BCAP*4);
  int*   gcur  = (int*)   alloc((size_t)NB*4);

  prep_w1     <<<5,          256, 0, stream>>>(W1, wt, gcur, NB);
  bin_scatter <<<NSC,        256, 0, stream>>>(esrc, edst, gcur, binned, E, NB);
  gemm1_kernel<<<NPB,        256, 0, stream>>>(x, wt, as1w, ad1w, h1b, as1, ad1,
                                               N, NT1, NPB);
  bucket_csr  <<<NB,         512, 0, stream>>>(binned, gcur, nodeptr, csr, N);
  agg1_kernel <<<(N+3)/4,    256, 0, stream>>>(nodeptr, csr, h1b, as1, ad1, b1, hrb, N);
  gemm2_kernel<<<(N+255)/256,256, 0, stream>>>(hrb, W2, as2w, ad2w, h2b, as2, ad2, N);
  agg2_kernel <<<(N+3)/4,    256, 0, stream>>>(nodeptr, csr, h2b, as2, ad2, b2, out, N);
}

// Round 16
// 175.536 us; speedup vs baseline: 1.0866x; 1.0472x over previous
//
#include <hip/hip_runtime.h>

// GAT 2-layer: N=100000, IN=256, L1: heads=8 x 8, L2: heads=1 x 40.
// R16: (1) bucket_csr FUSED into persistent gemm1 (bucket_csr is grid-starved
// standalone -- 391 blocks = 1.5/CU -- so fusing costs no occupancy; its ~12us
// latency hides under gemm1's tile loop). Stream: prep -> scatter ->
// [csr||gemm1] -> agg1 -> gemm2 -> agg2. (2) agg1 uint2 gathers: 4 edges in
// flight x 16 channel-quads (8B/lane), half the gather instructions.

#define L_IN   256
#define L_C1   64
#define L_H1   8
#define L_OUT  40
#define BCAP   5120     // bucket capacity (mean 4092, sigma ~64)

typedef __attribute__((ext_vector_type(8))) short short8;
typedef __attribute__((ext_vector_type(4))) float f32x4;

__device__ __forceinline__ float leaky(float x){ return fmaxf(x, 0.2f*x); }
__device__ __forceinline__ unsigned f2bf(float f){
  unsigned u = __float_as_uint(f);
  return (u + 0x7fffu + ((u >> 16) & 1u)) >> 16;     // RNE
}
__device__ __forceinline__ float bflo(unsigned u){ return __uint_as_float(u << 16); }
__device__ __forceinline__ float bfhi(unsigned u){ return __uint_as_float(u & 0xffff0000u); }

// ---------------- prep: W1 -> wt (bf16 transposed); block 4 zeros gcur ----------------
__global__ __launch_bounds__(256) void prep_w1(const float* __restrict__ W1,
                                               ushort* __restrict__ wt,
                                               int* __restrict__ gcur, int NB){
  const int t = threadIdx.x;
  if (blockIdx.x == 4){
    for (int i = t; i < NB; i += 256) gcur[i] = 0;
    return;
  }
  __shared__ float ws[64][65];
  const int kb = blockIdx.x;            // 4 blocks, one K-chunk each
  #pragma unroll
  for (int i = 0; i < 16; ++i){
    int idx = t + i*256;
    ws[idx >> 6][idx & 63] = W1[(size_t)(kb*64 + (idx >> 6))*64 + (idx & 63)];
  }
  __syncthreads();
  int c  = t >> 2;
  int j0 = (t & 3) * 16;
  ushort tmp[16];
  #pragma unroll
  for (int j = 0; j < 16; ++j) tmp[j] = (ushort)f2bf(ws[j0 + j][c]);
  uint4* dst = (uint4*)(wt + (size_t)c*256 + kb*64 + j0);
  dst[0] = *(uint4*)&tmp[0];
  dst[1] = *(uint4*)&tmp[8];
}

// ---------------- bin_scatter: standalone (6KB LDS -> 8 blocks/CU) ----------------
// Entry = src | (local_dst << 17)  [N < 131072].
__global__ __launch_bounds__(256) void bin_scatter(const int* __restrict__ esrc,
    const int* __restrict__ edst, int* __restrict__ gcur,
    unsigned* __restrict__ binned, int E, int NB){
  __shared__ int hist[512], rbase[512], cur[512];
  const int t  = threadIdx.x;
  const int e0 = blockIdx.x * 4096;
  hist[t] = 0; hist[t+256] = 0; cur[t] = 0; cur[t+256] = 0;
  __syncthreads();
  int sv[16], dv[16];
  const bool full = (e0 + 4096 <= E);
  if (full){
    #pragma unroll
    for (int j = 0; j < 4; ++j){
      int p4 = (e0 >> 2) + j*256 + t;
      int4 s4 = ((const int4*)esrc)[p4];
      int4 d4 = ((const int4*)edst)[p4];
      sv[4*j+0]=s4.x; sv[4*j+1]=s4.y; sv[4*j+2]=s4.z; sv[4*j+3]=s4.w;
      dv[4*j+0]=d4.x; dv[4*j+1]=d4.y; dv[4*j+2]=d4.z; dv[4*j+3]=d4.w;
      atomicAdd(&hist[d4.x >> 8], 1); atomicAdd(&hist[d4.y >> 8], 1);
      atomicAdd(&hist[d4.z >> 8], 1); atomicAdd(&hist[d4.w >> 8], 1);
    }
  } else {
    #pragma unroll
    for (int j = 0; j < 16; ++j){
      int idx = e0 + j*256 + t;
      if (idx < E){
        sv[j] = esrc[idx]; dv[j] = edst[idx];
        atomicAdd(&hist[dv[j] >> 8], 1);
      } else dv[j] = -1;
    }
  }
  __syncthreads();
  if (hist[t])                   rbase[t]     = atomicAdd(&gcur[t],     hist[t]);
  if (t+256 < NB && hist[t+256]) rbase[t+256] = atomicAdd(&gcur[t+256], hist[t+256]);
  __syncthreads();
  #pragma unroll
  for (int j = 0; j < 16; ++j){
    if (dv[j] >= 0){
      int b = dv[j] >> 8;
      int off = rbase[b] + atomicAdd(&cur[b], 1);
      if (off < BCAP)
        binned[(size_t)b*BCAP + off] =
          (unsigned)sv[j] | ((unsigned)(dv[j] & 255) << 17);
    }
  }
}

// ---------------- FUSED: bucket_csr (blocks 0..NBK-1) || persistent gemm1 ----------------
__global__ __launch_bounds__(256) void csr_gemm1(
    const unsigned* __restrict__ binned, const int* __restrict__ gcur,
    int2* __restrict__ nodeptr, int* __restrict__ csr, int NBK,
    const float* __restrict__ x, const ushort* __restrict__ wt,
    const float* __restrict__ atts, const float* __restrict__ attd,
    ushort* __restrict__ h1b, float* __restrict__ as1, float* __restrict__ ad1,
    int n, int ntiles, int npb)
{
  __shared__ __align__(16) char smem[43008];
  const int t   = threadIdx.x;
  const int bid = blockIdx.x;

  if (bid < NBK){
    // ---- bucket_csr path (LDS: ebuf 20.5KB + cnt/pref/cur 3KB) ----
    unsigned* ebuf = (unsigned*)smem;
    int* cnt  = (int*)(smem + BCAP*4);
    int* pref = cnt + 256;
    int* cur  = pref + 256;
    const int b = bid;
    int ne = gcur[b]; if (ne > BCAP) ne = BCAP;
    const int base = b * BCAP;
    cnt[t] = 0; cur[t] = 0;
    __syncthreads();
    for (int i = t; i < ne; i += 256){
      unsigned e = binned[base + i];
      ebuf[i] = e;
      atomicAdd(&cnt[(e >> 17) & 255u], 1);
    }
    __syncthreads();
    pref[t] = cnt[t];
    __syncthreads();
    for (int off = 1; off < 256; off <<= 1){
      int a = (t >= off) ? pref[t-off] : 0;
      __syncthreads();
      pref[t] += a;
      __syncthreads();
    }
    int excl = pref[t] - cnt[t];
    __syncthreads();
    pref[t] = excl;
    int d = (b << 8) + t;
    if (d < n) nodeptr[d] = make_int2(base + excl, cnt[t]);
    __syncthreads();
    for (int i = t; i < ne; i += 256){
      unsigned e = ebuf[i];
      int ln = (int)((e >> 17) & 255u);
      int pos = base + pref[ln] + atomicAdd(&cur[ln], 1);
      csr[pos] = (int)(e & 0x1FFFFu);
    }
    return;
  }

  // ---- persistent gemm1 path (LDS: ws 33792 + hs 9216 = 43008) ----
  ushort (*ws)[264] = (ushort(*)[264])(smem);
  ushort (*hs)[72]  = (ushort(*)[72]) (smem + 33792);
  const int wv = t >> 6;
  const int ln = t & 63;
  const int fr = ln & 15;
  const int fq = ln >> 4;

  #pragma unroll
  for (int i = 0; i < 8; ++i){
    int idx = t + i*256;
    int row = idx >> 5, c8 = idx & 31;
    *(uint4*)&ws[row][c8*8] = *(const uint4*)(wt + (size_t)row*256 + c8*8);
  }
  __syncthreads();                      // the only gemm1 barrier

  for (int tile = bid - NBK; tile < ntiles; tile += npb){
    const int rb = tile * 64;
    const int ar = rb + wv*16 + fr;
    const bool rv = ar < n;
    const float* xr = x + (size_t)(rv ? ar : 0) * L_IN;

    f32x4 acc[4];
    #pragma unroll
    for (int cb = 0; cb < 4; ++cb) acc[cb] = (f32x4){0.f,0.f,0.f,0.f};

    #pragma unroll
    for (int kk = 0; kk < 8; ++kk){
      const int k0 = kk*32 + fq*8;
      float4 a0 = make_float4(0.f,0.f,0.f,0.f), a1 = a0;
      if (rv){
        a0 = *(const float4*)(xr + k0);
        a1 = *(const float4*)(xr + k0 + 4);
      }
      uint4 au;
      au.x = f2bf(a0.x) | (f2bf(a0.y) << 16);
      au.y = f2bf(a0.z) | (f2bf(a0.w) << 16);
      au.z = f2bf(a1.x) | (f2bf(a1.y) << 16);
      au.w = f2bf(a1.z) | (f2bf(a1.w) << 16);
      short8 a = *(short8*)&au;
      #pragma unroll
      for (int cb = 0; cb < 4; ++cb){
        short8 b = *(const short8*)&ws[cb*16 + fr][k0];
        acc[cb] = __builtin_amdgcn_mfma_f32_16x16x32_bf16(a, b, acc[cb], 0, 0, 0);
      }
    }

    #pragma unroll
    for (int cb = 0; cb < 4; ++cb)
      #pragma unroll
      for (int r = 0; r < 4; ++r)
        hs[wv*16 + fq*4 + r][cb*16 + fr] = (ushort)f2bf(acc[cb][r]);

    #pragma unroll
    for (int i = 0; i < 2; ++i){
      int task = ln + i*64;
      int lrow = task >> 3;
      int sub  = task & 7;
      int row  = rb + wv*16 + lrow;
      if (row < n){
        uint4 u = *(const uint4*)&hs[wv*16 + lrow][sub*8];
        *(uint4*)(h1b + (size_t)row*L_C1 + sub*8) = u;
        float v0=bflo(u.x), v1=bfhi(u.x), v2=bflo(u.y), v3=bfhi(u.y);
        float v4=bflo(u.z), v5=bfhi(u.z), v6=bflo(u.w), v7=bfhi(u.w);
        const float* sa = atts + sub*8;
        const float* da = attd + sub*8;
        float ds = v0*sa[0]+v1*sa[1]+v2*sa[2]+v3*sa[3]+v4*sa[4]+v5*sa[5]+v6*sa[6]+v7*sa[7];
        float dd = v0*da[0]+v1*da[1]+v2*da[2]+v3*da[3]+v4*da[4]+v5*da[5]+v6*da[6]+v7*da[7];
        as1[(size_t)row*L_H1 + sub] = ds;
        ad1[(size_t)row*L_H1 + sub] = dd;
      }
    }
  }
}

// ---------------- AGG1: single-pass softmax-aggregate + bias + relu (bf16 out) ----------------
// uint2 gathers: 4 edges/step x 16 channel-quads (8B/lane).
__global__ __launch_bounds__(256) void agg1_kernel(
    const int2* __restrict__ nodeptr, const int* __restrict__ csr,
    const ushort* __restrict__ h1b, const float* __restrict__ as1,
    const float* __restrict__ ad1, const float* __restrict__ b1,
    ushort* __restrict__ hrb, int n)
{
  int wid  = (blockIdx.x*blockDim.x + threadIdx.x) >> 6;
  int lane = threadIdx.x & 63;
  if (wid >= n) return;
  int2 np  = nodeptr[wid];
  int beg  = np.x;
  int degt = np.y + 1;                    // + virtual self-loop

  const int h  = lane & 7;    // head (weight layout)
  const int eg = lane >> 3;   // edge-in-group (weight layout)
  const int cq = lane & 15;   // channel quad (acc layout): channels 4cq..4cq+3
  const int eq = lane >> 4;   // edge-in-step (acc layout, 0..3)
  const int hw = cq >> 1;     // head of this channel quad

  float adn = ad1[(size_t)wid*L_H1 + h];
  float a0 = 0.f, a1 = 0.f, a2 = 0.f, a3 = 0.f, sp = 0.f;

  #define A1_GRP_W(g, SRCV, WV)                                            \
    { int i_ = (g)*8 + eg;                                                 \
      SRCV = (i_ < degt-1) ? csr[beg + i_] : wid;                          \
      float l_ = (i_ < degt) ? leaky(as1[(size_t)SRCV*L_H1 + h] + adn)     \
                             : -1e30f;                                     \
      WV = __expf(l_); sp += WV; }
  #define A1_GRP_G(SRCV, WV)                                               \
    _Pragma("unroll")                                                      \
    for (int e0 = 0; e0 < 8; e0 += 4){                                     \
      int e_  = e0 + eq;                                                   \
      float we_ = __shfl(WV,   e_*8 + hw);                                 \
      int   se_ = __shfl(SRCV, e_*8);                                      \
      uint2 u_ = *(const uint2*)(h1b + (size_t)se_*L_C1 + cq*4);           \
      a0 += we_ * bflo(u_.x);                                              \
      a1 += we_ * bfhi(u_.x);                                              \
      a2 += we_ * bflo(u_.y);                                              \
      a3 += we_ * bfhi(u_.y);                                              \
    }

  if (degt <= 16){
    int s0, s1; float w0, w1;
    A1_GRP_W(0, s0, w0) A1_GRP_W(1, s1, w1)
    A1_GRP_G(s0, w0) A1_GRP_G(s1, w1)
  } else if (degt <= 24){
    int s0, s1, s2; float w0, w1, w2;
    A1_GRP_W(0, s0, w0) A1_GRP_W(1, s1, w1) A1_GRP_W(2, s2, w2)
    A1_GRP_G(s0, w0) A1_GRP_G(s1, w1) A1_GRP_G(s2, w2)
  } else {
    const int ngrp = (degt + 7) >> 3;
    for (int g = 0; g < ngrp; ++g){
      int sg; float wg;
      A1_GRP_W(g, sg, wg)
      A1_GRP_G(sg, wg)
    }
  }
  #undef A1_GRP_W
  #undef A1_GRP_G

  #pragma unroll
  for (int off = 8; off < 64; off <<= 1) sp += __shfl_xor(sp, off);
  float rinv = 1.0f / __shfl(sp, hw);
  a0 += __shfl_xor(a0, 16); a0 += __shfl_xor(a0, 32);
  a1 += __shfl_xor(a1, 16); a1 += __shfl_xor(a1, 32);
  a2 += __shfl_xor(a2, 16); a2 += __shfl_xor(a2, 32);
  a3 += __shfl_xor(a3, 16); a3 += __shfl_xor(a3, 32);
  if (lane < 16){
    float4 bv = *(const float4*)&b1[cq*4];
    float r0 = fmaxf(a0*rinv + bv.x, 0.f);
    float r1 = fmaxf(a1*rinv + bv.y, 0.f);
    float r2 = fmaxf(a2*rinv + bv.z, 0.f);
    float r3 = fmaxf(a3*rinv + bv.w, 0.f);
    uint2 o;
    o.x = f2bf(r0) | (f2bf(r1) << 16);
    o.y = f2bf(r2) | (f2bf(r3) << 16);
    *(uint2*)(hrb + (size_t)wid*L_C1 + cq*4) = o;
  }
}

// ---------------- GEMM2: h2 = hrelu @ W2 (+att dots), reg-resident rows ----------------
__global__ __launch_bounds__(256) void gemm2_kernel(
    const ushort* __restrict__ hrb, const float* __restrict__ W2,
    const float* __restrict__ atts2, const float* __restrict__ attd2,
    ushort* __restrict__ h2b, float* __restrict__ as2, float* __restrict__ ad2, int n)
{
  __shared__ float w2s[64*40];
  const int t = threadIdx.x;
  for (int i = t; i < 64*40; i += 256) w2s[i] = W2[i];
  __syncthreads();
  int row = blockIdx.x*256 + t;
  if (row >= n) return;

  uint4 rv[8];
  #pragma unroll
  for (int q = 0; q < 8; ++q)
    rv[q] = *(const uint4*)(hrb + (size_t)row*L_C1 + q*8);

  f32x4 acc4[10];
  #pragma unroll
  for (int j = 0; j < 10; ++j) acc4[j] = (f32x4){0.f,0.f,0.f,0.f};

  #pragma unroll
  for (int q = 0; q < 8; ++q){
    unsigned uu[4] = {rv[q].x, rv[q].y, rv[q].z, rv[q].w};
    #pragma unroll
    for (int d = 0; d < 4; ++d){
      int k = q*8 + d*2;
      float v0 = bflo(uu[d]), v1 = bfhi(uu[d]);
      const f32x4* w0 = (const f32x4*)&w2s[k*40];
      const f32x4* w1 = (const f32x4*)&w2s[(k+1)*40];
      #pragma unroll
      for (int j = 0; j < 10; ++j) acc4[j] += v0*w0[j] + v1*w1[j];
    }
  }

  float acc[40];
  #pragma unroll
  for (int j = 0; j < 10; ++j){
    acc[4*j+0]=acc4[j][0]; acc[4*j+1]=acc4[j][1];
    acc[4*j+2]=acc4[j][2]; acc[4*j+3]=acc4[j][3];
  }
  float ps = 0.f, pd = 0.f;
  #pragma unroll
  for (int j = 0; j < 40; ++j){ ps += acc[j]*atts2[j]; pd += acc[j]*attd2[j]; }
  unsigned pk[20];
  #pragma unroll
  for (int q = 0; q < 20; ++q) pk[q] = f2bf(acc[2*q]) | (f2bf(acc[2*q+1]) << 16);
  uint4* dst = (uint4*)(h2b + (size_t)row*L_OUT);
  #pragma unroll
  for (int q = 0; q < 5; ++q) dst[q] = make_uint4(pk[4*q],pk[4*q+1],pk[4*q+2],pk[4*q+3]);
  as2[row] = ps;
  ad2[row] = pd;
}

// ---------------- AGG2 + bias + log_softmax: 3-edge x 20-chpair, tiered ----------------
__global__ __launch_bounds__(256) void agg2_kernel(
    const int2* __restrict__ nodeptr, const int* __restrict__ csr,
    const ushort* __restrict__ h2b, const float* __restrict__ as2,
    const float* __restrict__ ad2, const float* __restrict__ b2,
    float* __restrict__ out, int n)
{
  int wid  = (blockIdx.x*blockDim.x + threadIdx.x) >> 6;
  int lane = threadIdx.x & 63;
  if (wid >= n) return;
  int2 np  = nodeptr[wid];
  int beg  = np.x;
  int degt = np.y + 1;

  const int eidx = (lane < 60) ? (lane / 20) : 0;   // edge-in-step (0..2)
  const int cq   = (lane < 60) ? (lane % 20) : 0;   // channel pair (0..19)

  float adn = ad2[wid];
  float ax = 0.f, ay = 0.f, sp = 0.f;

  #define A2_STEP(e_, SRCV, WV, CNT)                                       \
    { int ee_ = (e_);                                                      \
      int es_ = (ee_ < 64) ? ee_ : 63;                                     \
      float we_ = __shfl(WV,   es_);                                       \
      int   se_ = __shfl(SRCV, es_);                                       \
      we_ = (ee_ < (CNT)) ? we_ : 0.f;                                     \
      unsigned u_ = *(const unsigned*)(h2b + (size_t)se_*L_OUT + cq*2);    \
      ax += we_ * bflo(u_);                                                \
      ay += we_ * bfhi(u_); }

  if (degt <= 64){
    int i = lane;
    int src = (i < degt-1) ? csr[beg + i] : wid;
    float l = (i < degt) ? leaky(as2[src] + adn) : -1e30f;
    float w = __expf(l);
    sp = w;
    if (degt <= 18){
      #pragma unroll
      for (int j = 0; j < 2; ++j){
        A2_STEP(j*9 + 0*3 + eidx, src, w, degt)
        A2_STEP(j*9 + 1*3 + eidx, src, w, degt)
        A2_STEP(j*9 + 2*3 + eidx, src, w, degt)
      }
    } else if (degt <= 27){
      #pragma unroll
      for (int j = 0; j < 3; ++j){
        A2_STEP(j*9 + 0*3 + eidx, src, w, degt)
        A2_STEP(j*9 + 1*3 + eidx, src, w, degt)
        A2_STEP(j*9 + 2*3 + eidx, src, w, degt)
      }
    } else if (degt <= 36){
      #pragma unroll
      for (int j = 0; j < 4; ++j){
        A2_STEP(j*9 + 0*3 + eidx, src, w, degt)
        A2_STEP(j*9 + 1*3 + eidx, src, w, degt)
        A2_STEP(j*9 + 2*3 + eidx, src, w, degt)
      }
    } else {
      for (int e0 = 0; e0 < degt; e0 += 9){
        A2_STEP(e0 + 0*3 + eidx, src, w, degt)
        A2_STEP(e0 + 1*3 + eidx, src, w, degt)
        A2_STEP(e0 + 2*3 + eidx, src, w, degt)
      }
    }
  } else {
    const int ngrp = (degt + 63) >> 6;
    for (int g = 0; g < ngrp; ++g){
      int i = g*64 + lane;
      int src = (i < degt-1) ? csr[beg + i] : wid;
      float l = (i < degt) ? leaky(as2[src] + adn) : -1e30f;
      float w = __expf(l);
      sp += w;
      int cnt = degt - g*64; if (cnt > 64) cnt = 64;
      for (int e0 = 0; e0 < cnt; e0 += 9){
        A2_STEP(e0 + 0*3 + eidx, src, w, cnt)
        A2_STEP(e0 + 1*3 + eidx, src, w, cnt)
        A2_STEP(e0 + 2*3 + eidx, src, w, cnt)
      }
    }
  }
  #undef A2_STEP

  #pragma unroll
  for (int off = 1; off < 64; off <<= 1) sp += __shfl_xor(sp, off);
  float rinv = 1.0f / sp;

  float ax0 = __shfl(ax, cq), ax1 = __shfl(ax, cq+20), ax2 = __shfl(ax, cq+40);
  float ay0 = __shfl(ay, cq), ay1 = __shfl(ay, cq+20), ay2 = __shfl(ay, cq+40);
  float axs = (ax0 + ax1) + ax2;
  float ays = (ay0 + ay1) + ay2;

  bool act = (lane < 20);
  float o0 = axs*rinv + b2[cq*2];
  float o1 = ays*rinv + b2[cq*2+1];
  float mx = act ? fmaxf(o0, o1) : -1e30f;
  #pragma unroll
  for (int off = 1; off < 32; off <<= 1) mx = fmaxf(mx, __shfl_xor(mx, off));
  float ex = act ? (__expf(o0 - mx) + __expf(o1 - mx)) : 0.f;
  #pragma unroll
  for (int off = 1; off < 32; off <<= 1) ex += __shfl_xor(ex, off);
  float lse = mx + __logf(ex);
  if (act){
    float2 r = make_float2(o0 - lse, o1 - lse);
    *(float2*)(out + (size_t)wid*L_OUT + cq*2) = r;
  }
}

// ---------------- launch ----------------
extern "C" void kernel_launch(void* const* d_in, const int* in_sizes, int n_in,
                              void* d_out, int out_size, void* d_ws, size_t ws_size,
                              hipStream_t stream)
{
  const float* x    = (const float*)d_in[0];
  const int*   ei   = (const int*)  d_in[1];
  const float* W1   = (const float*)d_in[2];
  const float* as1w = (const float*)d_in[3];
  const float* ad1w = (const float*)d_in[4];
  const float* b1   = (const float*)d_in[5];
  const float* W2   = (const float*)d_in[6];
  const float* as2w = (const float*)d_in[7];
  const float* ad2w = (const float*)d_in[8];
  const float* b2   = (const float*)d_in[9];

  const int N = in_sizes[0] / L_IN;
  const int E = in_sizes[1] / 2;
  const int NB = (N + 255) >> 8;          // buckets of 256 nodes (<=512)
  const int NSC = (E + 4095) / 4096;      // scatter blocks
  const int NT1 = (N + 63) / 64;          // gemm1 tiles
  const int NPB = (NT1 < 768) ? NT1 : 768; // persistent gemm1 blocks
  const int* esrc = ei;
  const int* edst = ei + E;
  float* out = (float*)d_out;

  char* w = (char*)d_ws;
  auto alloc = [&](size_t bytes)->char*{
    char* p = w; w += (bytes + 255) & ~size_t(255); return p;
  };
  ushort* h1b  = (ushort*)alloc((size_t)N*L_C1*2);
  float*  as1  = (float*) alloc((size_t)N*L_H1*4);
  float*  ad1  = (float*) alloc((size_t)N*L_H1*4);
  // union: binned (NB*BCAP*4, dead after csr build) aliases hrb+h2b
  size_t union_sz = (size_t)N*L_C1*2 + (size_t)N*L_OUT*2;
  if (union_sz < (size_t)NB*BCAP*4) union_sz = (size_t)NB*BCAP*4;
  char*  ub    = alloc(union_sz);
  ushort* hrb  = (ushort*)ub;
  ushort* h2b  = (ushort*)(ub + (size_t)N*L_C1*2);
  unsigned* binned = (unsigned*)ub;
  float*  as2  = (float*) alloc((size_t)N*4);
  float*  ad2  = (float*) alloc((size_t)N*4);
  ushort* wt   = (ushort*)alloc((size_t)64*256*2);
  int2*  nodeptr=(int2*)  alloc((size_t)N*8);
  int*   csr   = (int*)   alloc((size_t)NB*BCAP*4);
  int*   gcur  = (int*)   alloc((size_t)NB*4);

  prep_w1     <<<5,          256, 0, stream>>>(W1, wt, gcur, NB);
  bin_scatter <<<NSC,        256, 0, stream>>>(esrc, edst, gcur, binned, E, NB);
  csr_gemm1   <<<NB + NPB,   256, 0, stream>>>(binned, gcur, nodeptr, csr, NB,
                                               x, wt, as1w, ad1w, h1b, as1, ad1,
                                               N, NT1, NPB);
  agg1_kernel <<<(N+3)/4,    256, 0, stream>>>(nodeptr, csr, h1b, as1, ad1, b1, hrb, N);
  gemm2_kernel<<<(N+255)/256,256, 0, stream>>>(hrb, W2, as2w, ad2w, h2b, as2, ad2, N);
  agg2_kernel <<<(N+3)/4,    256, 0, stream>>>(nodeptr, csr, h2b, as2, ad2, b2, out, N);
}